// Round 14
// baseline (199.521 us; speedup 1.0000x reference)
//
#include <hip/hip_runtime.h>

#define C_IN  128
#define C_HID 128
#define C_OUT 64

typedef __attribute__((ext_vector_type(8))) short short8;
typedef __attribute__((ext_vector_type(4))) float f32x4;

// bf16 helpers (RNE)
__device__ __forceinline__ unsigned f2bf(float f) {
    unsigned u = __float_as_uint(f);
    return (u + 0x7FFF + ((u >> 16) & 1)) >> 16;
}
__device__ __forceinline__ float bflo(unsigned t) { return __uint_as_float(t << 16); }
__device__ __forceinline__ float bfhi(unsigned t) { return __uint_as_float(t & 0xFFFF0000u); }

// ================= x f32 -> bf16 (packed), fused cnt zeroing =================

__global__ __launch_bounds__(256) void k_cvt(const float4* __restrict__ in, uint2* __restrict__ outp,
                                             int n4, int* __restrict__ cnt, int n) {
    int i = blockIdx.x * 256 + threadIdx.x;
    if (i < n) cnt[i] = 0;
    if (i < n4) {
        float4 v = in[i];
        uint2 o;
        o.x = (f2bf(v.y) << 16) | f2bf(v.x);
        o.y = (f2bf(v.w) << 16) | f2bf(v.z);
        outp[i] = o;
    }
}

// ================= XCD-partitioned CSR build =================
// group g = blockIdx&7 -> XCD g (round-robin dispatch heuristic; correctness-independent).
// Group g owns dst range [g*chunk, (g+1)*chunk): all atomics/stores to cnt/cursor/csr_src
// stay in ONE XCD's L2 -> no cross-XCD line bouncing. Each group streams the full edge list.

__global__ __launch_bounds__(256) void k_countP(const int* __restrict__ ei, int* __restrict__ cnt,
                                                int E, int n) {
    const int g = blockIdx.x & 7;
    const int bpg = gridDim.x >> 3;
    const int chunk = (n + 7) >> 3;
    const int lo = g * chunk, hi = min(lo + chunk, n);
    const int stride = bpg * 256;
    for (int e = (blockIdx.x >> 3) * 256 + threadIdx.x; e < E; e += stride) {
        int d = ei[E + e];
        if (d >= lo && d < hi) atomicAdd(&cnt[d], 1);   // L2-local atomic
    }
}

__global__ __launch_bounds__(256) void k_fillP(const int* __restrict__ ei, int* __restrict__ cursor,
                                               int* __restrict__ csr_src, int E, int n) {
    const int g = blockIdx.x & 7;
    const int bpg = gridDim.x >> 3;
    const int chunk = (n + 7) >> 3;
    const int lo = g * chunk, hi = min(lo + chunk, n);
    const int stride = bpg * 256;
    for (int e = (blockIdx.x >> 3) * 256 + threadIdx.x; e < E; e += stride) {
        int d = ei[E + e];
        int s = ei[e];
        if (d >= lo && d < hi) {
            int p = atomicAdd(&cursor[d], 1);           // L2-local atomic
            csr_src[p] = s;                             // L2-local line (one XCD per region)
        }
    }
}

__global__ __launch_bounds__(256) void k_dinv(const int* __restrict__ cnt, float* __restrict__ dinv, int n) {
    int i = blockIdx.x * 256 + threadIdx.x;
    if (i < n) dinv[i] = rsqrtf((float)(cnt[i] + 1));  // +1 self-loop
}

__global__ __launch_bounds__(256) void k_scan1(const int* __restrict__ cnt, int* __restrict__ row_ptr,
                                               int* __restrict__ bsum, int n) {
    __shared__ int s[256];
    int tid = threadIdx.x;
    int i = blockIdx.x * 256 + tid;
    int v = (i < n) ? cnt[i] : 0;
    s[tid] = v;
    __syncthreads();
    #pragma unroll
    for (int off = 1; off < 256; off <<= 1) {
        int t = (tid >= off) ? s[tid - off] : 0;
        __syncthreads();
        s[tid] += t;
        __syncthreads();
    }
    if (i < n) row_ptr[i] = s[tid] - v;
    if (tid == 255) bsum[blockIdx.x] = s[255];
}

__global__ __launch_bounds__(256) void k_scan2(const int* __restrict__ bsum, int* __restrict__ bpre, int nb) {
    __shared__ int s[256];
    int tid = threadIdx.x;
    int v = (tid < nb) ? bsum[tid] : 0;
    s[tid] = v;
    __syncthreads();
    #pragma unroll
    for (int off = 1; off < 256; off <<= 1) {
        int t = (tid >= off) ? s[tid - off] : 0;
        __syncthreads();
        s[tid] += t;
        __syncthreads();
    }
    if (tid < nb) bpre[tid] = s[tid] - v;
}

__global__ __launch_bounds__(256) void k_scan3(int* __restrict__ row_ptr, int* __restrict__ cursor,
                                               const int* __restrict__ bpre, int n, int E) {
    int i = blockIdx.x * 256 + threadIdx.x;
    if (i < n) {
        int r = row_ptr[i] + bpre[blockIdx.x];
        row_ptr[i] = r;
        cursor[i] = r;
    }
    if (i == 0) row_ptr[n] = E;
}

// ================= MFMA GEMM: H'bf16[M,N] = dinv[row] * (Xbf16[M,128] @ Wf32[128,N]) =================
// 256 thr = 4 waves; wave w owns 16-row strip (M % 16 == 0). mfma_f32_16x16x32_bf16.
// Output rows pre-scaled by dinv[row] -> aggregation needs NO per-edge coefficients:
//   agg[v] = dinv[v] * (h'[v] + sum_{s in N(v)} h'[s]) + bias.

template<int N>
__global__ __launch_bounds__(256) void k_gemm_mfma(const unsigned short* __restrict__ X,
                                                   const float* __restrict__ W,
                                                   const float* __restrict__ dinv,
                                                   unsigned short* __restrict__ H, int M) {
    constexpr int K = 128;
    constexpr int LDT = K + 8;                 // pad: 2-way-free b128 reads
    __shared__ unsigned short sWt[N * LDT];

    const int tid = threadIdx.x;
    // stage W transposed as bf16 (coalesced f32 reads)
    constexpr int NLOG = (N == 128) ? 7 : 6;
    for (int idx = tid; idx < K * N; idx += 256) {
        int k = idx >> NLOG, c = idx & (N - 1);
        sWt[c * LDT + k] = (unsigned short)f2bf(W[idx]);
    }
    __syncthreads();

    const int wave = __builtin_amdgcn_readfirstlane(tid >> 6);
    const int lane = tid & 63;
    const int m0 = blockIdx.x * 64 + wave * 16;
    if (m0 >= M) return;                        // no syncthreads after this point

    const int arow = lane & 15;
    const int koff = (lane >> 4) * 8;

    // A fragments: 16B each, k0 = 0,32,64,96
    const unsigned short* ap = X + (size_t)(m0 + arow) * K + koff;
    short8 a[4];
    #pragma unroll
    for (int q = 0; q < 4; ++q) a[q] = *(const short8*)(ap + q * 32);

    const int row0 = m0 + (lane >> 4) * 4;
    const float4 dv = *(const float4*)(dinv + row0);   // row0 % 4 == 0, dinv 16B-aligned

    #pragma unroll
    for (int ct = 0; ct < N / 16; ++ct) {
        const int bcol = ct * 16 + (lane & 15);
        const unsigned short* bp = &sWt[bcol * LDT + koff];
        f32x4 acc = {0.f, 0.f, 0.f, 0.f};
        #pragma unroll
        for (int q = 0; q < 4; ++q) {
            short8 b = *(const short8*)(bp + q * 32);
            acc = __builtin_amdgcn_mfma_f32_16x16x32_bf16(a[q], b, acc, 0, 0, 0);
        }
        const int col = ct * 16 + (lane & 15);
        #pragma unroll
        for (int r = 0; r < 4; ++r) {
            float dr = (r == 0) ? dv.x : (r == 1) ? dv.y : (r == 2) ? dv.z : dv.w;
            H[(size_t)(row0 + r) * N + col] = (unsigned short)f2bf(acc[r] * dr);
        }
    }
}

// ================= aggregation over pre-scaled bf16 h': wave owns G=4 nodes, U=16 batches =================
// acc[g] = h'[v] + sum h'[s]  (unweighted!) ; out = dinv[v]*acc + bias (f32 epilogue).
// C=128: lane owns cols (2l,2l+1): one uint gather/lane. C=64: lane owns col l: ushort gather.
// OUTBF: store packed bf16 (feeds next MFMA GEMM); else f32.

template<int C, bool RELU, bool OUTBF>
__global__ __launch_bounds__(256) void k_agg(const void* __restrict__ hraw,
                                             const int* __restrict__ row_ptr,
                                             const int* __restrict__ csr_src,
                                             const float* __restrict__ dinv,
                                             const float* __restrict__ bias,
                                             void* __restrict__ agg, int n) {
    constexpr int G = 4;
    constexpr int U = 16;
    constexpr int VPC = C / 64;          // 2 (C=128) or 1 (C=64)
    const int lane = threadIdx.x & 63;
    const int wv = __builtin_amdgcn_readfirstlane(threadIdx.x >> 6);
    const int v0 = (blockIdx.x * 4 + wv) * G;
    if (v0 >= n) return;

    const unsigned*       hu = (const unsigned*)hraw;        // C=128 view
    const unsigned short* hs = (const unsigned short*)hraw;  // C=64 view

    int rp[G + 1];
    #pragma unroll
    for (int g = 0; g <= G; ++g) rp[g] = row_ptr[min(v0 + g, n)];

    float dd[G];
    float acc[G][VPC];
    #pragma unroll
    for (int g = 0; g < G; ++g) {
        #pragma unroll
        for (int u = 0; u < VPC; ++u) acc[g][u] = 0.f;
        dd[g] = 0.f;
        if (v0 + g < n) {
            dd[g] = dinv[v0 + g];
            if (VPC == 2) {
                unsigned t = hu[(size_t)(v0 + g) * 64 + lane];
                acc[g][0] = bflo(t);
                acc[g][1] = bfhi(t);
            } else {
                acc[g][0] = bflo(hs[(size_t)(v0 + g) * 64 + lane]);
            }
        }
    }

    const int e = rp[G];
    for (int j0 = rp[0]; j0 < e; j0 += U) {
        int ss[U];
        #pragma unroll
        for (int u = 0; u < U; ++u) {
            int s = csr_src[j0 + u];          // contiguous scalar loads
                                              // (<=60B overread into next ws buffer)
            ss[u] = (j0 + u < e) ? s : 0;     // clamp OOB slots
        }
        float hv[U][VPC];
        #pragma unroll
        for (int u = 0; u < U; ++u) {
            if (VPC == 2) {
                unsigned t = hu[(size_t)ss[u] * 64 + lane];
                hv[u][0] = bflo(t);
                hv[u][1] = bfhi(t);
            } else {
                hv[u][0] = bflo(hs[(size_t)ss[u] * 64 + lane]);
            }
        }
        #pragma unroll
        for (int u = 0; u < U; ++u) {
            const int jj = j0 + u;
            #pragma unroll
            for (int g = 0; g < G; ++g) {
                bool in_g = (jj >= rp[g]) && (jj < rp[g + 1]);  // wave-uniform; OOB -> none
                float cg = in_g ? 1.f : 0.f;
                #pragma unroll
                for (int u2 = 0; u2 < VPC; ++u2) acc[g][u2] += cg * hv[u][u2];
            }
        }
    }

    #pragma unroll
    for (int g = 0; g < G; ++g) {
        if (v0 + g < n) {
            if (VPC == 2) {
                float2 bv = ((const float2*)bias)[lane];   // bias[2l], bias[2l+1]
                float ox = acc[g][0] * dd[g] + bv.x;
                float oy = acc[g][1] * dd[g] + bv.y;
                if (RELU) { ox = fmaxf(ox, 0.f); oy = fmaxf(oy, 0.f); }
                if (OUTBF) {
                    ((unsigned*)agg)[(size_t)(v0 + g) * 64 + lane] = (f2bf(oy) << 16) | f2bf(ox);
                } else {
                    ((float2*)agg)[(size_t)(v0 + g) * 64 + lane] = make_float2(ox, oy);
                }
            } else {
                float o = acc[g][0] * dd[g] + bias[lane];
                if (RELU) o = fmaxf(o, 0.f);
                if (OUTBF) ((unsigned short*)agg)[(size_t)(v0 + g) * 64 + lane] = (unsigned short)f2bf(o);
                else       ((float*)agg)[(size_t)(v0 + g) * 64 + lane] = o;
            }
        }
    }
}

// ================= launch =================

extern "C" void kernel_launch(void* const* d_in, const int* in_sizes, int n_in,
                              void* d_out, int out_size, void* d_ws, size_t ws_size,
                              hipStream_t stream) {
    const float* x  = (const float*)d_in[0];
    const int*   ei = (const int*)d_in[1];
    const float* W1 = (const float*)d_in[2];
    const float* b1 = (const float*)d_in[3];
    const float* W2 = (const float*)d_in[4];
    const float* b2 = (const float*)d_in[5];
    float* out = (float*)d_out;

    const int N = in_sizes[0] / C_IN;   // 50000
    const int E = in_sizes[1] / 2;      // 800000

    // 16B-aligned workspace layout
    char* base = (char*)d_ws;
    size_t off = 0;
    auto alloc = [&](size_t bytes) {
        char* q = base + off;
        off = (off + bytes + 15) & ~(size_t)15;
        return q;
    };
    int*   cnt      = (int*)  alloc((size_t)N * 4);
    float* dinv     = (float*)alloc((size_t)N * 4);
    int*   row_ptr  = (int*)  alloc((size_t)(N + 1) * 4);
    int*   cursor   = (int*)  alloc((size_t)N * 4);
    int*   bsum     = (int*)  alloc(256 * 4);
    int*   bpre     = (int*)  alloc(256 * 4);
    int*   csr_src  = (int*)  alloc((size_t)E * 4);
    unsigned short* xb   = (unsigned short*)alloc((size_t)N * C_IN * 2);   // bf16 x
    unsigned short* h    = (unsigned short*)alloc((size_t)N * C_HID * 2);  // bf16 h' / h2'
    unsigned short* agg1 = (unsigned short*)alloc((size_t)N * C_HID * 2);  // bf16 agg1
    unsigned short* h2   = h;  // layer-2 h' reuses h (dead after agg128)

    dim3 blk(256);
    const int nbS = (N + 255) / 256;

    // fused: bf16 conversion of x + cnt zeroing
    k_cvt<<<((N * C_IN / 4) + 255) / 256, blk, 0, stream>>>((const float4*)x, (uint2*)xb,
                                                            N * C_IN / 4, cnt, N);

    // XCD-partitioned CSR build: 8 groups x 64 blocks
    k_countP<<<8 * 64, blk, 0, stream>>>(ei, cnt, E, N);
    k_dinv <<<nbS, blk, 0, stream>>>(cnt, dinv, N);
    k_scan1<<<nbS, blk, 0, stream>>>(cnt, row_ptr, bsum, N);
    k_scan2<<<1, blk, 0, stream>>>(bsum, bpre, nbS);
    k_scan3<<<nbS, blk, 0, stream>>>(row_ptr, cursor, bpre, N, E);
    k_fillP<<<8 * 64, blk, 0, stream>>>(ei, cursor, csr_src, E, N);

    const int gblocks = (N + 63) / 64;
    const int ablocks = (N + 15) / 16;   // 4 waves x G=4 nodes per block

    // layer 1: h' = dinv * bf16(xb @ W1) ; agg1 = bf16(relu(dinv*(sum h') + b1))
    k_gemm_mfma<C_HID><<<gblocks, blk, 0, stream>>>(xb, W1, dinv, h, N);
    k_agg<C_HID, true, true><<<ablocks, blk, 0, stream>>>(h, row_ptr, csr_src, dinv, b1, agg1, N);

    // layer 2: h2' = dinv * bf16(agg1 @ W2) ; out = dinv*(sum h2') + b2
    k_gemm_mfma<C_OUT><<<gblocks, blk, 0, stream>>>(agg1, W2, dinv, h2, N);
    k_agg<C_OUT, false, false><<<ablocks, blk, 0, stream>>>(h2, row_ptr, csr_src, dinv, b2, out, N);
}

// Round 15
// 144.854 us; speedup vs baseline: 1.3774x; 1.3774x over previous
//
#include <hip/hip_runtime.h>

#define C_IN  128
#define C_HID 128
#define C_OUT 64
#define TILE  4096

typedef __attribute__((ext_vector_type(8))) short short8;
typedef __attribute__((ext_vector_type(4))) float f32x4;

// bf16 helpers (RNE)
__device__ __forceinline__ unsigned f2bf(float f) {
    unsigned u = __float_as_uint(f);
    return (u + 0x7FFF + ((u >> 16) & 1)) >> 16;
}
__device__ __forceinline__ float bflo(unsigned t) { return __uint_as_float(t << 16); }
__device__ __forceinline__ float bfhi(unsigned t) { return __uint_as_float(t & 0xFFFF0000u); }

// ================= x f32 -> bf16 (packed) =================

__global__ __launch_bounds__(256) void k_cvt(const float4* __restrict__ in, uint2* __restrict__ outp, int n4) {
    int i = blockIdx.x * 256 + threadIdx.x;
    if (i < n4) {
        float4 v = in[i];
        uint2 o;
        o.x = (f2bf(v.y) << 16) | f2bf(v.x);
        o.y = (f2bf(v.w) << 16) | f2bf(v.z);
        outp[i] = o;
    }
}

// ================= counting-sort CSR build =================
// bucket b = dsts [b*256, b*256+256); tile t = edges [t*TILE, (t+1)*TILE).
// No global atomics; all global writes are dense/coalesced or confined per-block regions.

// 1) per-tile bucket histogram: histT[b*NT + t]
__global__ __launch_bounds__(256) void k_histo(const int* __restrict__ ei, int* __restrict__ histT,
                                               int E, int NT, int NB) {
    __shared__ int h[256];
    const int t = blockIdx.x;
    const int tid = threadIdx.x;
    h[tid] = 0;
    __syncthreads();
    const int end = min((t + 1) * TILE, E);
    for (int i = t * TILE + tid; i < end; i += 256)
        atomicAdd(&h[ei[E + i] >> 8], 1);          // LDS atomic
    __syncthreads();
    if (tid < NB) histT[tid * NT + t] = h[tid];
}

// 2) exclusive scan of histT (bucket-major) via 3-kernel machinery
__global__ __launch_bounds__(256) void k_scan1(const int* __restrict__ in, int* __restrict__ outp,
                                               int* __restrict__ bsum, int n) {
    __shared__ int s[256];
    int tid = threadIdx.x;
    int i = blockIdx.x * 256 + tid;
    int v = (i < n) ? in[i] : 0;
    s[tid] = v;
    __syncthreads();
    #pragma unroll
    for (int off = 1; off < 256; off <<= 1) {
        int t = (tid >= off) ? s[tid - off] : 0;
        __syncthreads();
        s[tid] += t;
        __syncthreads();
    }
    if (i < n) outp[i] = s[tid] - v;              // exclusive, block-local
    if (tid == 255) bsum[blockIdx.x] = s[255];
}

__global__ __launch_bounds__(256) void k_scan2(const int* __restrict__ bsum, int* __restrict__ bpre, int nb) {
    __shared__ int s[256];
    int tid = threadIdx.x;
    int v = (tid < nb) ? bsum[tid] : 0;
    s[tid] = v;
    __syncthreads();
    #pragma unroll
    for (int off = 1; off < 256; off <<= 1) {
        int t = (tid >= off) ? s[tid - off] : 0;
        __syncthreads();
        s[tid] += t;
        __syncthreads();
    }
    if (tid < nb) bpre[tid] = s[tid] - v;
}

__global__ __launch_bounds__(256) void k_scanAdd(int* __restrict__ outp, const int* __restrict__ bpre, int n) {
    int i = blockIdx.x * 256 + threadIdx.x;
    if (i < n) outp[i] += bpre[blockIdx.x];
}

// 3) reorder: scatter packed (src<<8)|(dst&255) into per-bucket runs (dense lines)
__global__ __launch_bounds__(256) void k_reorder(const int* __restrict__ ei,
                                                 const int* __restrict__ tileOff,
                                                 unsigned* __restrict__ tmp,
                                                 int E, int NT, int NB) {
    __shared__ int cur[256];
    const int t = blockIdx.x;
    const int tid = threadIdx.x;
    if (tid < NB) cur[tid] = tileOff[tid * NT + t];
    __syncthreads();
    const int end = min((t + 1) * TILE, E);
    for (int i = t * TILE + tid; i < end; i += 256) {
        int d = ei[E + i];
        int s = ei[i];
        int p = atomicAdd(&cur[d >> 8], 1);       // LDS atomic, global slot
        tmp[p] = ((unsigned)s << 8) | (unsigned)(d & 255);
    }
}

// 4) per-bucket finalize: row_ptr + dinv (coalesced) and csr_src (region-confined scatter)
__global__ __launch_bounds__(256) void k_bucket(const unsigned* __restrict__ tmp,
                                                const int* __restrict__ tileOff,
                                                int* __restrict__ row_ptr,
                                                float* __restrict__ dinv,
                                                int* __restrict__ csr_src,
                                                int E, int NT, int NB, int n) {
    __shared__ int c[256], ssc[256], lcur[256];
    const int b = blockIdx.x;
    const int tid = threadIdx.x;
    const int rbeg = tileOff[b * NT];
    const int rend = (b + 1 < NB) ? tileOff[(b + 1) * NT] : E;

    c[tid] = 0;
    __syncthreads();
    for (int i = rbeg + tid; i < rend; i += 256)
        atomicAdd(&c[tmp[i] & 255], 1);           // LDS histogram
    __syncthreads();

    // exclusive block scan of c
    ssc[tid] = c[tid];
    __syncthreads();
    #pragma unroll
    for (int off = 1; off < 256; off <<= 1) {
        int t2 = (tid >= off) ? ssc[tid - off] : 0;
        __syncthreads();
        ssc[tid] += t2;
        __syncthreads();
    }
    const int ex = ssc[tid] - c[tid];

    const int d = b * 256 + tid;
    if (d < n) {
        row_ptr[d] = rbeg + ex;
        dinv[d] = rsqrtf((float)(c[tid] + 1));    // +1 self-loop
        if (d == n - 1) row_ptr[n] = E;
    }
    lcur[tid] = rbeg + ex;
    __syncthreads();

    for (int i = rbeg + tid; i < rend; i += 256) {
        unsigned w = tmp[i];
        int p = atomicAdd(&lcur[w & 255], 1);     // LDS atomic
        csr_src[p] = (int)(w >> 8);               // write stays inside this bucket's region
    }
}

// ================= MFMA GEMM: H'bf16[M,N] = dinv[row] * (Xbf16[M,128] @ Wf32[128,N]) =================
// 256 thr = 4 waves; wave w owns 16-row strip (M % 16 == 0). mfma_f32_16x16x32_bf16.
// Output rows pre-scaled by dinv[row] -> aggregation needs NO per-edge coefficients:
//   agg[v] = dinv[v] * (h'[v] + sum_{s in N(v)} h'[s]) + bias.

template<int N>
__global__ __launch_bounds__(256) void k_gemm_mfma(const unsigned short* __restrict__ X,
                                                   const float* __restrict__ W,
                                                   const float* __restrict__ dinv,
                                                   unsigned short* __restrict__ H, int M) {
    constexpr int K = 128;
    constexpr int LDT = K + 8;                 // pad: 2-way-free b128 reads
    __shared__ unsigned short sWt[N * LDT];

    const int tid = threadIdx.x;
    // stage W transposed as bf16 (coalesced f32 reads)
    constexpr int NLOG = (N == 128) ? 7 : 6;
    for (int idx = tid; idx < K * N; idx += 256) {
        int k = idx >> NLOG, c = idx & (N - 1);
        sWt[c * LDT + k] = (unsigned short)f2bf(W[idx]);
    }
    __syncthreads();

    const int wave = __builtin_amdgcn_readfirstlane(tid >> 6);
    const int lane = tid & 63;
    const int m0 = blockIdx.x * 64 + wave * 16;
    if (m0 >= M) return;                        // no syncthreads after this point

    const int arow = lane & 15;
    const int koff = (lane >> 4) * 8;

    // A fragments: 16B each, k0 = 0,32,64,96
    const unsigned short* ap = X + (size_t)(m0 + arow) * K + koff;
    short8 a[4];
    #pragma unroll
    for (int q = 0; q < 4; ++q) a[q] = *(const short8*)(ap + q * 32);

    const int row0 = m0 + (lane >> 4) * 4;
    const float4 dv = *(const float4*)(dinv + row0);   // row0 % 4 == 0, dinv 16B-aligned

    #pragma unroll
    for (int ct = 0; ct < N / 16; ++ct) {
        const int bcol = ct * 16 + (lane & 15);
        const unsigned short* bp = &sWt[bcol * LDT + koff];
        f32x4 acc = {0.f, 0.f, 0.f, 0.f};
        #pragma unroll
        for (int q = 0; q < 4; ++q) {
            short8 bq = *(const short8*)(bp + q * 32);
            acc = __builtin_amdgcn_mfma_f32_16x16x32_bf16(a[q], bq, acc, 0, 0, 0);
        }
        const int col = ct * 16 + (lane & 15);
        #pragma unroll
        for (int r = 0; r < 4; ++r) {
            float dr = (r == 0) ? dv.x : (r == 1) ? dv.y : (r == 2) ? dv.z : dv.w;
            H[(size_t)(row0 + r) * N + col] = (unsigned short)f2bf(acc[r] * dr);
        }
    }
}

// ================= aggregation over pre-scaled bf16 h': wave owns G=4 nodes, U=16 batches =================
// acc[g] = h'[v] + sum h'[s]  (unweighted!) ; out = dinv[v]*acc + bias (f32 epilogue).
// C=128: lane owns cols (2l,2l+1): one uint gather/lane. C=64: lane owns col l: ushort gather.
// OUTBF: store packed bf16 (feeds next MFMA GEMM); else f32.

template<int C, bool RELU, bool OUTBF>
__global__ __launch_bounds__(256) void k_agg(const void* __restrict__ hraw,
                                             const int* __restrict__ row_ptr,
                                             const int* __restrict__ csr_src,
                                             const float* __restrict__ dinv,
                                             const float* __restrict__ bias,
                                             void* __restrict__ agg, int n) {
    constexpr int G = 4;
    constexpr int U = 16;
    constexpr int VPC = C / 64;          // 2 (C=128) or 1 (C=64)
    const int lane = threadIdx.x & 63;
    const int wv = __builtin_amdgcn_readfirstlane(threadIdx.x >> 6);
    const int v0 = (blockIdx.x * 4 + wv) * G;
    if (v0 >= n) return;

    const unsigned*       hu = (const unsigned*)hraw;        // C=128 view
    const unsigned short* hs = (const unsigned short*)hraw;  // C=64 view

    int rp[G + 1];
    #pragma unroll
    for (int g = 0; g <= G; ++g) rp[g] = row_ptr[min(v0 + g, n)];

    float dd[G];
    float acc[G][VPC];
    #pragma unroll
    for (int g = 0; g < G; ++g) {
        #pragma unroll
        for (int u = 0; u < VPC; ++u) acc[g][u] = 0.f;
        dd[g] = 0.f;
        if (v0 + g < n) {
            dd[g] = dinv[v0 + g];
            if (VPC == 2) {
                unsigned t = hu[(size_t)(v0 + g) * 64 + lane];
                acc[g][0] = bflo(t);
                acc[g][1] = bfhi(t);
            } else {
                acc[g][0] = bflo(hs[(size_t)(v0 + g) * 64 + lane]);
            }
        }
    }

    const int e = rp[G];
    for (int j0 = rp[0]; j0 < e; j0 += U) {
        int ss[U];
        #pragma unroll
        for (int u = 0; u < U; ++u) {
            int s = csr_src[j0 + u];          // contiguous scalar loads
                                              // (<=60B overread into next ws buffer)
            ss[u] = (j0 + u < e) ? s : 0;     // clamp OOB slots
        }
        float hv[U][VPC];
        #pragma unroll
        for (int u = 0; u < U; ++u) {
            if (VPC == 2) {
                unsigned t = hu[(size_t)ss[u] * 64 + lane];
                hv[u][0] = bflo(t);
                hv[u][1] = bfhi(t);
            } else {
                hv[u][0] = bflo(hs[(size_t)ss[u] * 64 + lane]);
            }
        }
        #pragma unroll
        for (int u = 0; u < U; ++u) {
            const int jj = j0 + u;
            #pragma unroll
            for (int g = 0; g < G; ++g) {
                bool in_g = (jj >= rp[g]) && (jj < rp[g + 1]);  // wave-uniform; OOB -> none
                float cg = in_g ? 1.f : 0.f;
                #pragma unroll
                for (int u2 = 0; u2 < VPC; ++u2) acc[g][u2] += cg * hv[u][u2];
            }
        }
    }

    #pragma unroll
    for (int g = 0; g < G; ++g) {
        if (v0 + g < n) {
            if (VPC == 2) {
                float2 bv = ((const float2*)bias)[lane];   // bias[2l], bias[2l+1]
                float ox = acc[g][0] * dd[g] + bv.x;
                float oy = acc[g][1] * dd[g] + bv.y;
                if (RELU) { ox = fmaxf(ox, 0.f); oy = fmaxf(oy, 0.f); }
                if (OUTBF) {
                    ((unsigned*)agg)[(size_t)(v0 + g) * 64 + lane] = (f2bf(oy) << 16) | f2bf(ox);
                } else {
                    ((float2*)agg)[(size_t)(v0 + g) * 64 + lane] = make_float2(ox, oy);
                }
            } else {
                float o = acc[g][0] * dd[g] + bias[lane];
                if (RELU) o = fmaxf(o, 0.f);
                if (OUTBF) ((unsigned short*)agg)[(size_t)(v0 + g) * 64 + lane] = (unsigned short)f2bf(o);
                else       ((float*)agg)[(size_t)(v0 + g) * 64 + lane] = o;
            }
        }
    }
}

// ================= launch =================

extern "C" void kernel_launch(void* const* d_in, const int* in_sizes, int n_in,
                              void* d_out, int out_size, void* d_ws, size_t ws_size,
                              hipStream_t stream) {
    const float* x  = (const float*)d_in[0];
    const int*   ei = (const int*)d_in[1];
    const float* W1 = (const float*)d_in[2];
    const float* b1 = (const float*)d_in[3];
    const float* W2 = (const float*)d_in[4];
    const float* b2 = (const float*)d_in[5];
    float* out = (float*)d_out;

    const int N = in_sizes[0] / C_IN;   // 50000
    const int E = in_sizes[1] / 2;      // 800000
    const int NT = (E + TILE - 1) / TILE;   // 196 tiles
    const int NB = (N + 255) >> 8;          // 196 buckets
    const int M2 = NB * NT;                 // 38416 scan elements

    // 16B-aligned workspace layout
    char* base = (char*)d_ws;
    size_t off = 0;
    auto alloc = [&](size_t bytes) {
        char* q = base + off;
        off = (off + bytes + 15) & ~(size_t)15;
        return q;
    };
    int*   histT    = (int*)  alloc((size_t)M2 * 4);
    int*   tileOff  = (int*)  alloc((size_t)M2 * 4);
    int*   bsumH    = (int*)  alloc(256 * 4);
    int*   bpreH    = (int*)  alloc(256 * 4);
    unsigned* tmp   = (unsigned*)alloc((size_t)E * 4);
    int*   row_ptr  = (int*)  alloc((size_t)(N + 1) * 4);
    float* dinv     = (float*)alloc((size_t)N * 4);
    int*   csr_src  = (int*)  alloc((size_t)E * 4);
    unsigned short* xb   = (unsigned short*)alloc((size_t)N * C_IN * 2);   // bf16 x
    unsigned short* h    = (unsigned short*)alloc((size_t)N * C_HID * 2);  // bf16 h' / h2'
    unsigned short* agg1 = (unsigned short*)alloc((size_t)N * C_HID * 2);  // bf16 agg1
    unsigned short* h2   = h;  // layer-2 h' reuses h (dead after agg128)

    dim3 blk(256);
    const int nbS2 = (M2 + 255) / 256;      // 151 scan blocks

    k_cvt<<<((N * C_IN / 4) + 255) / 256, blk, 0, stream>>>((const float4*)x, (uint2*)xb, N * C_IN / 4);

    // counting-sort CSR build (no global atomics)
    k_histo  <<<NT, blk, 0, stream>>>(ei, histT, E, NT, NB);
    k_scan1  <<<nbS2, blk, 0, stream>>>(histT, tileOff, bsumH, M2);
    k_scan2  <<<1, blk, 0, stream>>>(bsumH, bpreH, nbS2);
    k_scanAdd<<<nbS2, blk, 0, stream>>>(tileOff, bpreH, M2);
    k_reorder<<<NT, blk, 0, stream>>>(ei, tileOff, tmp, E, NT, NB);
    k_bucket <<<NB, blk, 0, stream>>>(tmp, tileOff, row_ptr, dinv, csr_src, E, NT, NB, N);

    const int gblocks = (N + 63) / 64;
    const int ablocks = (N + 15) / 16;   // 4 waves x G=4 nodes per block

    // layer 1: h' = dinv * bf16(xb @ W1) ; agg1 = bf16(relu(dinv*(sum h') + b1))
    k_gemm_mfma<C_HID><<<gblocks, blk, 0, stream>>>(xb, W1, dinv, h, N);
    k_agg<C_HID, true, true><<<ablocks, blk, 0, stream>>>(h, row_ptr, csr_src, dinv, b1, agg1, N);

    // layer 2: h2' = dinv * bf16(agg1 @ W2) ; out = dinv*(sum h2') + b2
    k_gemm_mfma<C_OUT><<<gblocks, blk, 0, stream>>>(agg1, W2, dinv, h2, N);
    k_agg<C_OUT, false, false><<<ablocks, blk, 0, stream>>>(h2, row_ptr, csr_src, dinv, b2, out, N);
}

// Round 16
// 124.043 us; speedup vs baseline: 1.6085x; 1.1678x over previous
//
#include <hip/hip_runtime.h>

#define C_IN  128
#define C_HID 128
#define C_OUT 64
#define TILE  4096

typedef __attribute__((ext_vector_type(8))) short short8;
typedef __attribute__((ext_vector_type(4))) float f32x4;

// bf16 helpers (RNE)
__device__ __forceinline__ unsigned f2bf(float f) {
    unsigned u = __float_as_uint(f);
    return (u + 0x7FFF + ((u >> 16) & 1)) >> 16;
}
__device__ __forceinline__ float bflo(unsigned t) { return __uint_as_float(t << 16); }
__device__ __forceinline__ float bfhi(unsigned t) { return __uint_as_float(t & 0xFFFF0000u); }

// ================= x f32 -> bf16 (packed) =================

__global__ __launch_bounds__(256) void k_cvt(const float4* __restrict__ in, uint2* __restrict__ outp, int n4) {
    int i = blockIdx.x * 256 + threadIdx.x;
    if (i < n4) {
        float4 v = in[i];
        uint2 o;
        o.x = (f2bf(v.y) << 16) | f2bf(v.x);
        o.y = (f2bf(v.w) << 16) | f2bf(v.z);
        outp[i] = o;
    }
}

// ================= counting-sort CSR build (R15-proven) =================
// bucket b = dsts [b*256, b*256+256); tile t = edges [t*TILE, (t+1)*TILE).
// No global atomics; all global writes are dense/coalesced or confined per-block regions.

__global__ __launch_bounds__(256) void k_histo(const int* __restrict__ ei, int* __restrict__ histT,
                                               int E, int NT, int NB) {
    __shared__ int h[256];
    const int t = blockIdx.x;
    const int tid = threadIdx.x;
    h[tid] = 0;
    __syncthreads();
    const int end = min((t + 1) * TILE, E);
    for (int i = t * TILE + tid; i < end; i += 256)
        atomicAdd(&h[ei[E + i] >> 8], 1);          // LDS atomic
    __syncthreads();
    if (tid < NB) histT[tid * NT + t] = h[tid];
}

__global__ __launch_bounds__(256) void k_scan1(const int* __restrict__ in, int* __restrict__ outp,
                                               int* __restrict__ bsum, int n) {
    __shared__ int s[256];
    int tid = threadIdx.x;
    int i = blockIdx.x * 256 + tid;
    int v = (i < n) ? in[i] : 0;
    s[tid] = v;
    __syncthreads();
    #pragma unroll
    for (int off = 1; off < 256; off <<= 1) {
        int t = (tid >= off) ? s[tid - off] : 0;
        __syncthreads();
        s[tid] += t;
        __syncthreads();
    }
    if (i < n) outp[i] = s[tid] - v;              // exclusive, block-local
    if (tid == 255) bsum[blockIdx.x] = s[255];
}

__global__ __launch_bounds__(256) void k_scan2(const int* __restrict__ bsum, int* __restrict__ bpre, int nb) {
    __shared__ int s[256];
    int tid = threadIdx.x;
    int v = (tid < nb) ? bsum[tid] : 0;
    s[tid] = v;
    __syncthreads();
    #pragma unroll
    for (int off = 1; off < 256; off <<= 1) {
        int t = (tid >= off) ? s[tid - off] : 0;
        __syncthreads();
        s[tid] += t;
        __syncthreads();
    }
    if (tid < nb) bpre[tid] = s[tid] - v;
}

__global__ __launch_bounds__(256) void k_scanAdd(int* __restrict__ outp, const int* __restrict__ bpre, int n) {
    int i = blockIdx.x * 256 + threadIdx.x;
    if (i < n) outp[i] += bpre[blockIdx.x];
}

__global__ __launch_bounds__(256) void k_reorder(const int* __restrict__ ei,
                                                 const int* __restrict__ tileOff,
                                                 unsigned* __restrict__ tmp,
                                                 int E, int NT, int NB) {
    __shared__ int cur[256];
    const int t = blockIdx.x;
    const int tid = threadIdx.x;
    if (tid < NB) cur[tid] = tileOff[tid * NT + t];
    __syncthreads();
    const int end = min((t + 1) * TILE, E);
    for (int i = t * TILE + tid; i < end; i += 256) {
        int d = ei[E + i];
        int s = ei[i];
        int p = atomicAdd(&cur[d >> 8], 1);       // LDS atomic, global slot
        tmp[p] = ((unsigned)s << 8) | (unsigned)(d & 255);
    }
}

__global__ __launch_bounds__(256) void k_bucket(const unsigned* __restrict__ tmp,
                                                const int* __restrict__ tileOff,
                                                int* __restrict__ row_ptr,
                                                float* __restrict__ dinv,
                                                int* __restrict__ csr_src,
                                                int E, int NT, int NB, int n) {
    __shared__ int c[256], ssc[256], lcur[256];
    const int b = blockIdx.x;
    const int tid = threadIdx.x;
    const int rbeg = tileOff[b * NT];
    const int rend = (b + 1 < NB) ? tileOff[(b + 1) * NT] : E;

    c[tid] = 0;
    __syncthreads();
    for (int i = rbeg + tid; i < rend; i += 256)
        atomicAdd(&c[tmp[i] & 255], 1);           // LDS histogram
    __syncthreads();

    ssc[tid] = c[tid];
    __syncthreads();
    #pragma unroll
    for (int off = 1; off < 256; off <<= 1) {
        int t2 = (tid >= off) ? ssc[tid - off] : 0;
        __syncthreads();
        ssc[tid] += t2;
        __syncthreads();
    }
    const int ex = ssc[tid] - c[tid];

    const int d = b * 256 + tid;
    if (d < n) {
        row_ptr[d] = rbeg + ex;
        dinv[d] = rsqrtf((float)(c[tid] + 1));    // +1 self-loop
        if (d == n - 1) row_ptr[n] = E;
    }
    lcur[tid] = rbeg + ex;
    __syncthreads();

    for (int i = rbeg + tid; i < rend; i += 256) {
        unsigned w = tmp[i];
        int p = atomicAdd(&lcur[w & 255], 1);     // LDS atomic
        csr_src[p] = (int)(w >> 8);               // write stays inside this bucket's region
    }
}

// ================= MFMA GEMM: H'bf16[M,N] = dinv[row] * (Xbf16[M,128] @ Wf32[128,N]) =================
// 256 thr = 4 waves; wave w owns 16-row strip (M % 16 == 0). mfma_f32_16x16x32_bf16.
// Output rows pre-scaled by dinv[row] -> aggregation needs NO per-edge coefficients:
//   agg[v] = dinv[v] * (h'[v] + sum_{s in N(v)} h'[s]) + bias.

template<int N>
__global__ __launch_bounds__(256) void k_gemm_mfma(const unsigned short* __restrict__ X,
                                                   const float* __restrict__ W,
                                                   const float* __restrict__ dinv,
                                                   unsigned short* __restrict__ H, int M) {
    constexpr int K = 128;
    constexpr int LDT = K + 8;                 // pad: 2-way-free b128 reads
    __shared__ unsigned short sWt[N * LDT];

    const int tid = threadIdx.x;
    constexpr int NLOG = (N == 128) ? 7 : 6;
    for (int idx = tid; idx < K * N; idx += 256) {
        int k = idx >> NLOG, c = idx & (N - 1);
        sWt[c * LDT + k] = (unsigned short)f2bf(W[idx]);
    }
    __syncthreads();

    const int wave = __builtin_amdgcn_readfirstlane(tid >> 6);
    const int lane = tid & 63;
    const int m0 = blockIdx.x * 64 + wave * 16;
    if (m0 >= M) return;                        // no syncthreads after this point

    const int arow = lane & 15;
    const int koff = (lane >> 4) * 8;

    const unsigned short* ap = X + (size_t)(m0 + arow) * K + koff;
    short8 a[4];
    #pragma unroll
    for (int q = 0; q < 4; ++q) a[q] = *(const short8*)(ap + q * 32);

    const int row0 = m0 + (lane >> 4) * 4;
    const float4 dv = *(const float4*)(dinv + row0);   // row0 % 4 == 0, dinv 16B-aligned

    #pragma unroll
    for (int ct = 0; ct < N / 16; ++ct) {
        const int bcol = ct * 16 + (lane & 15);
        const unsigned short* bp = &sWt[bcol * LDT + koff];
        f32x4 acc = {0.f, 0.f, 0.f, 0.f};
        #pragma unroll
        for (int q = 0; q < 4; ++q) {
            short8 bq = *(const short8*)(bp + q * 32);
            acc = __builtin_amdgcn_mfma_f32_16x16x32_bf16(a[q], bq, acc, 0, 0, 0);
        }
        const int col = ct * 16 + (lane & 15);
        #pragma unroll
        for (int r = 0; r < 4; ++r) {
            float dr = (r == 0) ? dv.x : (r == 1) ? dv.y : (r == 2) ? dv.z : dv.w;
            H[(size_t)(row0 + r) * N + col] = (unsigned short)f2bf(acc[r] * dr);
        }
    }
}

// ================= aggregation: G=1 — one wave per node, unweighted sum =================
// acc = h'[v] + sum_{j in [e0,e1)} h'[csr[j]] ; out = dinv[v]*acc + bias (f32 epilogue).
// Full U=16 batches: plain adds (no routing, no masks). Boundary batch: clamp to row v
// (L1-hot) + one fmaf mask per edge. ~5 VALU/edge vs ~27 with G=4 interval routing.

template<int C, bool RELU, bool OUTBF>
__global__ __launch_bounds__(256) void k_agg(const void* __restrict__ hraw,
                                             const int* __restrict__ row_ptr,
                                             const int* __restrict__ csr_src,
                                             const float* __restrict__ dinv,
                                             const float* __restrict__ bias,
                                             void* __restrict__ agg, int n) {
    constexpr int U = 16;
    constexpr int VPC = C / 64;          // 2 (C=128) or 1 (C=64)
    const int lane = threadIdx.x & 63;
    const int wv = __builtin_amdgcn_readfirstlane(threadIdx.x >> 6);
    const int v = blockIdx.x * 4 + wv;
    if (v >= n) return;

    const unsigned*       hu = (const unsigned*)hraw;        // C=128 view
    const unsigned short* hs = (const unsigned short*)hraw;  // C=64 view

    const int e0 = row_ptr[v], e1 = row_ptr[v + 1];
    const float dd = dinv[v];

    float acc[VPC];
    if (VPC == 2) {
        unsigned t = hu[(size_t)v * 64 + lane];
        acc[0] = bflo(t);
        acc[1] = bfhi(t);
    } else {
        acc[0] = bflo(hs[(size_t)v * 64 + lane]);
    }

    int j0 = e0;
    for (; j0 + U <= e1; j0 += U) {              // full batches: no masks, no multiplies
        int ss[U];
        #pragma unroll
        for (int u = 0; u < U; ++u) ss[u] = csr_src[j0 + u];   // contiguous scalar loads
        float hv[U][VPC];
        #pragma unroll
        for (int u = 0; u < U; ++u) {
            if (VPC == 2) {
                unsigned t = hu[(size_t)ss[u] * 64 + lane];
                hv[u][0] = bflo(t);
                hv[u][1] = bfhi(t);
            } else {
                hv[u][0] = bflo(hs[(size_t)ss[u] * 64 + lane]);
            }
        }
        #pragma unroll
        for (int u = 0; u < U; ++u) {
            acc[0] += hv[u][0];
            if (VPC == 2) acc[1] += hv[u][1];
        }
    }
    if (j0 < e1) {                               // one boundary batch per node
        int ss[U];
        #pragma unroll
        for (int u = 0; u < U; ++u) {
            int sraw = csr_src[j0 + u];          // <=60B overread into next ws buffer
            ss[u] = (j0 + u < e1) ? sraw : v;    // clamp OOB to self row (L1-hot)
        }
        float hv[U][VPC];
        #pragma unroll
        for (int u = 0; u < U; ++u) {
            if (VPC == 2) {
                unsigned t = hu[(size_t)ss[u] * 64 + lane];
                hv[u][0] = bflo(t);
                hv[u][1] = bfhi(t);
            } else {
                hv[u][0] = bflo(hs[(size_t)ss[u] * 64 + lane]);
            }
        }
        #pragma unroll
        for (int u = 0; u < U; ++u) {
            float m = (j0 + u < e1) ? 1.f : 0.f;
            acc[0] = fmaf(m, hv[u][0], acc[0]);
            if (VPC == 2) acc[1] = fmaf(m, hv[u][1], acc[1]);
        }
    }

    if (VPC == 2) {
        float2 bv = ((const float2*)bias)[lane];   // bias[2l], bias[2l+1]
        float ox = acc[0] * dd + bv.x;
        float oy = acc[1] * dd + bv.y;
        if (RELU) { ox = fmaxf(ox, 0.f); oy = fmaxf(oy, 0.f); }
        if (OUTBF) {
            ((unsigned*)agg)[(size_t)v * 64 + lane] = (f2bf(oy) << 16) | f2bf(ox);
        } else {
            ((float2*)agg)[(size_t)v * 64 + lane] = make_float2(ox, oy);
        }
    } else {
        float o = acc[0] * dd + bias[lane];
        if (RELU) o = fmaxf(o, 0.f);
        if (OUTBF) ((unsigned short*)agg)[(size_t)v * 64 + lane] = (unsigned short)f2bf(o);
        else       ((float*)agg)[(size_t)v * 64 + lane] = o;
    }
}

// ================= launch =================

extern "C" void kernel_launch(void* const* d_in, const int* in_sizes, int n_in,
                              void* d_out, int out_size, void* d_ws, size_t ws_size,
                              hipStream_t stream) {
    const float* x  = (const float*)d_in[0];
    const int*   ei = (const int*)d_in[1];
    const float* W1 = (const float*)d_in[2];
    const float* b1 = (const float*)d_in[3];
    const float* W2 = (const float*)d_in[4];
    const float* b2 = (const float*)d_in[5];
    float* out = (float*)d_out;

    const int N = in_sizes[0] / C_IN;   // 50000
    const int E = in_sizes[1] / 2;      // 800000
    const int NT = (E + TILE - 1) / TILE;   // 196 tiles
    const int NB = (N + 255) >> 8;          // 196 buckets
    const int M2 = NB * NT;                 // 38416 scan elements

    // 16B-aligned workspace layout
    char* base = (char*)d_ws;
    size_t off = 0;
    auto alloc = [&](size_t bytes) {
        char* q = base + off;
        off = (off + bytes + 15) & ~(size_t)15;
        return q;
    };
    int*   histT    = (int*)  alloc((size_t)M2 * 4);
    int*   tileOff  = (int*)  alloc((size_t)M2 * 4);
    int*   bsumH    = (int*)  alloc(256 * 4);
    int*   bpreH    = (int*)  alloc(256 * 4);
    unsigned* tmp   = (unsigned*)alloc((size_t)E * 4);
    int*   row_ptr  = (int*)  alloc((size_t)(N + 1) * 4);
    float* dinv     = (float*)alloc((size_t)N * 4);
    int*   csr_src  = (int*)  alloc((size_t)E * 4);
    unsigned short* xb   = (unsigned short*)alloc((size_t)N * C_IN * 2);   // bf16 x
    unsigned short* h    = (unsigned short*)alloc((size_t)N * C_HID * 2);  // bf16 h' / h2'
    unsigned short* agg1 = (unsigned short*)alloc((size_t)N * C_HID * 2);  // bf16 agg1
    unsigned short* h2   = h;  // layer-2 h' reuses h (dead after agg128)

    dim3 blk(256);
    const int nbS2 = (M2 + 255) / 256;      // 151 scan blocks

    k_cvt<<<((N * C_IN / 4) + 255) / 256, blk, 0, stream>>>((const float4*)x, (uint2*)xb, N * C_IN / 4);

    // counting-sort CSR build (no global atomics)
    k_histo  <<<NT, blk, 0, stream>>>(ei, histT, E, NT, NB);
    k_scan1  <<<nbS2, blk, 0, stream>>>(histT, tileOff, bsumH, M2);
    k_scan2  <<<1, blk, 0, stream>>>(bsumH, bpreH, nbS2);
    k_scanAdd<<<nbS2, blk, 0, stream>>>(tileOff, bpreH, M2);
    k_reorder<<<NT, blk, 0, stream>>>(ei, tileOff, tmp, E, NT, NB);
    k_bucket <<<NB, blk, 0, stream>>>(tmp, tileOff, row_ptr, dinv, csr_src, E, NT, NB, N);

    const int gblocks = (N + 63) / 64;
    const int ablocks = (N + 3) / 4;     // 4 waves x 1 node per block

    // layer 1: h' = dinv * bf16(xb @ W1) ; agg1 = bf16(relu(dinv*(sum h') + b1))
    k_gemm_mfma<C_HID><<<gblocks, blk, 0, stream>>>(xb, W1, dinv, h, N);
    k_agg<C_HID, true, true><<<ablocks, blk, 0, stream>>>(h, row_ptr, csr_src, dinv, b1, agg1, N);

    // layer 2: h2' = dinv * bf16(agg1 @ W2) ; out = dinv*(sum h2') + b2
    k_gemm_mfma<C_OUT><<<gblocks, blk, 0, stream>>>(agg1, W2, dinv, h2, N);
    k_agg<C_OUT, false, false><<<ablocks, blk, 0, stream>>>(h2, row_ptr, csr_src, dinv, b2, out, N);
}

// Round 17
// 118.155 us; speedup vs baseline: 1.6886x; 1.0498x over previous
//
#include <hip/hip_runtime.h>

#define C_IN  128
#define C_HID 128
#define C_OUT 64
#define TILE  4096

typedef __attribute__((ext_vector_type(8))) short short8;
typedef __attribute__((ext_vector_type(4))) float f32x4;

// bf16 helpers (RNE)
__device__ __forceinline__ unsigned f2bf(float f) {
    unsigned u = __float_as_uint(f);
    return (u + 0x7FFF + ((u >> 16) & 1)) >> 16;
}
__device__ __forceinline__ float bflo(unsigned t) { return __uint_as_float(t << 16); }
__device__ __forceinline__ float bfhi(unsigned t) { return __uint_as_float(t & 0xFFFF0000u); }

// 256-wide exclusive block scan (Hillis-Steele in LDS). After return, s[255] = total.
__device__ __forceinline__ int block_exscan(int v, int* s) {
    const int tid = threadIdx.x;
    s[tid] = v;
    __syncthreads();
    #pragma unroll
    for (int off = 1; off < 256; off <<= 1) {
        int t = (tid >= off) ? s[tid - off] : 0;
        __syncthreads();
        s[tid] += t;
        __syncthreads();
    }
    return s[tid] - v;
}

// ================= fused: histo (blocks [0,NT)) ∥ x->bf16 cvt (blocks [NT,...)) =================

__global__ __launch_bounds__(256) void k_cvt_histo(const float4* __restrict__ in, uint2* __restrict__ outp,
                                                   int n4, const int* __restrict__ ei,
                                                   int* __restrict__ histT, int E, int NT, int NB) {
    const int tid = threadIdx.x;
    if ((int)blockIdx.x < NT) {
        // per-tile bucket histogram: histT[b*NT + t]
        __shared__ int h[256];
        const int t = blockIdx.x;
        h[tid] = 0;
        __syncthreads();
        const int end = min((t + 1) * TILE, E);
        for (int i = t * TILE + tid; i < end; i += 256)
            atomicAdd(&h[ei[E + i] >> 8], 1);          // LDS atomic
        __syncthreads();
        if (tid < NB) histT[tid * NT + t] = h[tid];
    } else {
        int i = ((int)blockIdx.x - NT) * 256 + tid;
        if (i < n4) {
            float4 v = in[i];
            uint2 o;
            o.x = (f2bf(v.y) << 16) | f2bf(v.x);
            o.y = (f2bf(v.w) << 16) | f2bf(v.z);
            outp[i] = o;
        }
    }
}

// ================= per-bucket tile scan: tilePrefix[b][t] (exclusive over t) + BT[b] =================

__global__ __launch_bounds__(256) void k_tilescan(const int* __restrict__ histT,
                                                  int* __restrict__ tilePrefix,
                                                  int* __restrict__ BT, int NT, int NB) {
    __shared__ int s[256];
    const int b = blockIdx.x;
    const int tid = threadIdx.x;
    int v = (tid < NT) ? histT[b * NT + tid] : 0;
    int ex = block_exscan(v, s);
    if (tid < NT) tilePrefix[b * NT + tid] = ex;
    if (tid == 255) BT[b] = s[255];                    // bucket total
}

// ================= reorder: scatter packed (src<<8)|(dst&255) into per-bucket runs =================
// Global offsets reconstructed in-block: base[b] = exscan(BT)[b]; cur = base + tilePrefix.

__global__ __launch_bounds__(256) void k_reorder(const int* __restrict__ ei,
                                                 const int* __restrict__ tilePrefix,
                                                 const int* __restrict__ BT,
                                                 unsigned* __restrict__ tmp,
                                                 int E, int NT, int NB) {
    __shared__ int s[256];
    __shared__ int cur[256];
    const int t = blockIdx.x;
    const int tid = threadIdx.x;
    int v = (tid < NB) ? BT[tid] : 0;
    int base = block_exscan(v, s);
    if (tid < NB) cur[tid] = base + tilePrefix[tid * NT + t];
    __syncthreads();
    const int end = min((t + 1) * TILE, E);
    for (int i = t * TILE + tid; i < end; i += 256) {
        int d = ei[E + i];
        int sv = ei[i];
        int p = atomicAdd(&cur[d >> 8], 1);            // LDS atomic, global slot
        tmp[p] = ((unsigned)sv << 8) | (unsigned)(d & 255);
    }
}

// ================= per-bucket finalize: row_ptr + dinv (coalesced), csr_src (region-confined) =================

__global__ __launch_bounds__(256) void k_bucket(const unsigned* __restrict__ tmp,
                                                const int* __restrict__ BT,
                                                int* __restrict__ row_ptr,
                                                float* __restrict__ dinv,
                                                int* __restrict__ csr_src,
                                                int E, int NB, int n) {
    __shared__ int sA[256], c[256], ssc[256], lcur[256];
    const int b = blockIdx.x;
    const int tid = threadIdx.x;

    int v = (tid < NB) ? BT[tid] : 0;
    (void)block_exscan(v, sA);                         // sA[i] = inclusive scan of BT
    const int vb = BT[b];
    const int rbeg = sA[b] - vb;                       // exclusive prefix at b
    const int rend = rbeg + vb;

    c[tid] = 0;
    __syncthreads();
    for (int i = rbeg + tid; i < rend; i += 256)
        atomicAdd(&c[tmp[i] & 255], 1);                // LDS histogram
    __syncthreads();

    int ex = block_exscan(c[tid], ssc);

    const int d = b * 256 + tid;
    if (d < n) {
        row_ptr[d] = rbeg + ex;
        dinv[d] = rsqrtf((float)(c[tid] + 1));         // +1 self-loop
        if (d == n - 1) row_ptr[n] = E;
    }
    lcur[tid] = rbeg + ex;
    __syncthreads();

    for (int i = rbeg + tid; i < rend; i += 256) {
        unsigned w = tmp[i];
        int p = atomicAdd(&lcur[w & 255], 1);          // LDS atomic
        csr_src[p] = (int)(w >> 8);                    // stays inside this bucket's region
    }
}

// ================= MFMA GEMM: H'bf16[M,N] = dinv[row] * (Xbf16[M,128] @ Wf32[128,N]) =================
// 256 thr = 4 waves; wave w owns 16-row strip (M % 16 == 0). mfma_f32_16x16x32_bf16.

template<int N>
__global__ __launch_bounds__(256) void k_gemm_mfma(const unsigned short* __restrict__ X,
                                                   const float* __restrict__ W,
                                                   const float* __restrict__ dinv,
                                                   unsigned short* __restrict__ H, int M) {
    constexpr int K = 128;
    constexpr int LDT = K + 8;                 // pad: 2-way-free b128 reads
    __shared__ unsigned short sWt[N * LDT];

    const int tid = threadIdx.x;
    constexpr int NLOG = (N == 128) ? 7 : 6;
    for (int idx = tid; idx < K * N; idx += 256) {
        int k = idx >> NLOG, c = idx & (N - 1);
        sWt[c * LDT + k] = (unsigned short)f2bf(W[idx]);
    }
    __syncthreads();

    const int wave = __builtin_amdgcn_readfirstlane(tid >> 6);
    const int lane = tid & 63;
    const int m0 = blockIdx.x * 64 + wave * 16;
    if (m0 >= M) return;                        // no syncthreads after this point

    const int arow = lane & 15;
    const int koff = (lane >> 4) * 8;

    const unsigned short* ap = X + (size_t)(m0 + arow) * K + koff;
    short8 a[4];
    #pragma unroll
    for (int q = 0; q < 4; ++q) a[q] = *(const short8*)(ap + q * 32);

    const int row0 = m0 + (lane >> 4) * 4;
    const float4 dv = *(const float4*)(dinv + row0);   // row0 % 4 == 0, dinv 16B-aligned

    #pragma unroll
    for (int ct = 0; ct < N / 16; ++ct) {
        const int bcol = ct * 16 + (lane & 15);
        const unsigned short* bp = &sWt[bcol * LDT + koff];
        f32x4 acc = {0.f, 0.f, 0.f, 0.f};
        #pragma unroll
        for (int q = 0; q < 4; ++q) {
            short8 bq = *(const short8*)(bp + q * 32);
            acc = __builtin_amdgcn_mfma_f32_16x16x32_bf16(a[q], bq, acc, 0, 0, 0);
        }
        const int col = ct * 16 + (lane & 15);
        #pragma unroll
        for (int r = 0; r < 4; ++r) {
            float dr = (r == 0) ? dv.x : (r == 1) ? dv.y : (r == 2) ? dv.z : dv.w;
            H[(size_t)(row0 + r) * N + col] = (unsigned short)f2bf(acc[r] * dr);
        }
    }
}

// ================= aggregation: G=1 — one wave per node, unweighted sum (R16-proven) =================

template<int C, bool RELU, bool OUTBF>
__global__ __launch_bounds__(256) void k_agg(const void* __restrict__ hraw,
                                             const int* __restrict__ row_ptr,
                                             const int* __restrict__ csr_src,
                                             const float* __restrict__ dinv,
                                             const float* __restrict__ bias,
                                             void* __restrict__ agg, int n) {
    constexpr int U = 16;
    constexpr int VPC = C / 64;          // 2 (C=128) or 1 (C=64)
    const int lane = threadIdx.x & 63;
    const int wv = __builtin_amdgcn_readfirstlane(threadIdx.x >> 6);
    const int v = blockIdx.x * 4 + wv;
    if (v >= n) return;

    const unsigned*       hu = (const unsigned*)hraw;        // C=128 view
    const unsigned short* hs = (const unsigned short*)hraw;  // C=64 view

    const int e0 = row_ptr[v], e1 = row_ptr[v + 1];
    const float dd = dinv[v];

    float acc[VPC];
    if (VPC == 2) {
        unsigned t = hu[(size_t)v * 64 + lane];
        acc[0] = bflo(t);
        acc[1] = bfhi(t);
    } else {
        acc[0] = bflo(hs[(size_t)v * 64 + lane]);
    }

    int j0 = e0;
    for (; j0 + U <= e1; j0 += U) {              // full batches: no masks, no multiplies
        int ss[U];
        #pragma unroll
        for (int u = 0; u < U; ++u) ss[u] = csr_src[j0 + u];   // contiguous scalar loads
        float hv[U][VPC];
        #pragma unroll
        for (int u = 0; u < U; ++u) {
            if (VPC == 2) {
                unsigned t = hu[(size_t)ss[u] * 64 + lane];
                hv[u][0] = bflo(t);
                hv[u][1] = bfhi(t);
            } else {
                hv[u][0] = bflo(hs[(size_t)ss[u] * 64 + lane]);
            }
        }
        #pragma unroll
        for (int u = 0; u < U; ++u) {
            acc[0] += hv[u][0];
            if (VPC == 2) acc[1] += hv[u][1];
        }
    }
    if (j0 < e1) {                               // one boundary batch per node
        int ss[U];
        #pragma unroll
        for (int u = 0; u < U; ++u) {
            int sraw = csr_src[j0 + u];          // <=60B overread into next ws buffer
            ss[u] = (j0 + u < e1) ? sraw : v;    // clamp OOB to self row (L1-hot)
        }
        float hv[U][VPC];
        #pragma unroll
        for (int u = 0; u < U; ++u) {
            if (VPC == 2) {
                unsigned t = hu[(size_t)ss[u] * 64 + lane];
                hv[u][0] = bflo(t);
                hv[u][1] = bfhi(t);
            } else {
                hv[u][0] = bflo(hs[(size_t)ss[u] * 64 + lane]);
            }
        }
        #pragma unroll
        for (int u = 0; u < U; ++u) {
            float m = (j0 + u < e1) ? 1.f : 0.f;
            acc[0] = fmaf(m, hv[u][0], acc[0]);
            if (VPC == 2) acc[1] = fmaf(m, hv[u][1], acc[1]);
        }
    }

    if (VPC == 2) {
        float2 bv = ((const float2*)bias)[lane];   // bias[2l], bias[2l+1]
        float ox = acc[0] * dd + bv.x;
        float oy = acc[1] * dd + bv.y;
        if (RELU) { ox = fmaxf(ox, 0.f); oy = fmaxf(oy, 0.f); }
        if (OUTBF) {
            ((unsigned*)agg)[(size_t)v * 64 + lane] = (f2bf(oy) << 16) | f2bf(ox);
        } else {
            ((float2*)agg)[(size_t)v * 64 + lane] = make_float2(ox, oy);
        }
    } else {
        float o = acc[0] * dd + bias[lane];
        if (RELU) o = fmaxf(o, 0.f);
        if (OUTBF) ((unsigned short*)agg)[(size_t)v * 64 + lane] = (unsigned short)f2bf(o);
        else       ((float*)agg)[(size_t)v * 64 + lane] = o;
    }
}

// ================= launch =================

extern "C" void kernel_launch(void* const* d_in, const int* in_sizes, int n_in,
                              void* d_out, int out_size, void* d_ws, size_t ws_size,
                              hipStream_t stream) {
    const float* x  = (const float*)d_in[0];
    const int*   ei = (const int*)d_in[1];
    const float* W1 = (const float*)d_in[2];
    const float* b1 = (const float*)d_in[3];
    const float* W2 = (const float*)d_in[4];
    const float* b2 = (const float*)d_in[5];
    float* out = (float*)d_out;

    const int N = in_sizes[0] / C_IN;   // 50000
    const int E = in_sizes[1] / 2;      // 800000
    const int NT = (E + TILE - 1) / TILE;   // 196 tiles   (<=256 required)
    const int NB = (N + 255) >> 8;          // 196 buckets (<=256 required)
    const int M2 = NB * NT;

    // 16B-aligned workspace layout
    char* base = (char*)d_ws;
    size_t off = 0;
    auto alloc = [&](size_t bytes) {
        char* q = base + off;
        off = (off + bytes + 15) & ~(size_t)15;
        return q;
    };
    int*   histT      = (int*)  alloc((size_t)M2 * 4);
    int*   tilePrefix = (int*)  alloc((size_t)M2 * 4);
    int*   BT         = (int*)  alloc(256 * 4);
    unsigned* tmp     = (unsigned*)alloc((size_t)E * 4);
    int*   row_ptr    = (int*)  alloc((size_t)(N + 1) * 4);
    float* dinv       = (float*)alloc((size_t)N * 4);
    int*   csr_src    = (int*)  alloc((size_t)E * 4);
    unsigned short* xb   = (unsigned short*)alloc((size_t)N * C_IN * 2);   // bf16 x
    unsigned short* h    = (unsigned short*)alloc((size_t)N * C_HID * 2);  // bf16 h' / h2'
    unsigned short* agg1 = (unsigned short*)alloc((size_t)N * C_HID * 2);  // bf16 agg1
    unsigned short* h2   = h;  // layer-2 h' reuses h (dead after agg128)

    dim3 blk(256);
    const int n4 = N * C_IN / 4;
    const int cvtBlocks = (n4 + 255) / 256;

    // 1) fused histo ∥ cvt
    k_cvt_histo<<<NT + cvtBlocks, blk, 0, stream>>>((const float4*)x, (uint2*)xb, n4,
                                                    ei, histT, E, NT, NB);
    // 2) per-bucket tile scan (+ bucket totals)
    k_tilescan<<<NB, blk, 0, stream>>>(histT, tilePrefix, BT, NT, NB);
    // 3) reorder into bucket runs
    k_reorder<<<NT, blk, 0, stream>>>(ei, tilePrefix, BT, tmp, E, NT, NB);
    // 4) per-bucket finalize: row_ptr, dinv, csr_src
    k_bucket<<<NB, blk, 0, stream>>>(tmp, BT, row_ptr, dinv, csr_src, E, NB, N);

    const int gblocks = (N + 63) / 64;
    const int ablocks = (N + 3) / 4;     // 4 waves x 1 node per block

    // layer 1: h' = dinv * bf16(xb @ W1) ; agg1 = bf16(relu(dinv*(sum h') + b1))
    k_gemm_mfma<C_HID><<<gblocks, blk, 0, stream>>>(xb, W1, dinv, h, N);
    k_agg<C_HID, true, true><<<ablocks, blk, 0, stream>>>(h, row_ptr, csr_src, dinv, b1, agg1, N);

    // layer 2: h2' = dinv * bf16(agg1 @ W2) ; out = dinv*(sum h2') + b2
    k_gemm_mfma<C_OUT><<<gblocks, blk, 0, stream>>>(agg1, W2, dinv, h2, N);
    k_agg<C_OUT, false, false><<<ablocks, blk, 0, stream>>>(h2, row_ptr, csr_src, dinv, b2, out, N);
}

// Round 18
// 112.720 us; speedup vs baseline: 1.7701x; 1.0482x over previous
//
#include <hip/hip_runtime.h>

#define C_IN  128
#define C_HID 128
#define C_OUT 64
#define TILE  4096
#define BCAP  6144   // per-bucket LDS staging capacity (mean 4082, sd ~64; fallback if exceeded)

typedef __attribute__((ext_vector_type(8))) short short8;
typedef __attribute__((ext_vector_type(4))) float f32x4;

// bf16 helpers (RNE)
__device__ __forceinline__ unsigned f2bf(float f) {
    unsigned u = __float_as_uint(f);
    return (u + 0x7FFF + ((u >> 16) & 1)) >> 16;
}
__device__ __forceinline__ float bflo(unsigned t) { return __uint_as_float(t << 16); }
__device__ __forceinline__ float bfhi(unsigned t) { return __uint_as_float(t & 0xFFFF0000u); }

// 256-wide exclusive block scan (Hillis-Steele in LDS). After return, s[255] = total.
__device__ __forceinline__ int block_exscan(int v, int* s) {
    const int tid = threadIdx.x;
    s[tid] = v;
    __syncthreads();
    #pragma unroll
    for (int off = 1; off < 256; off <<= 1) {
        int t = (tid >= off) ? s[tid - off] : 0;
        __syncthreads();
        s[tid] += t;
        __syncthreads();
    }
    return s[tid] - v;
}

// 512-wide variant (values beyond the first 256 lanes are zero-padded by callers).
__device__ __forceinline__ int block_exscan512(int v, int* s) {
    const int tid = threadIdx.x;
    s[tid] = v;
    __syncthreads();
    #pragma unroll
    for (int off = 1; off < 512; off <<= 1) {
        int t = (tid >= off) ? s[tid - off] : 0;
        __syncthreads();
        s[tid] += t;
        __syncthreads();
    }
    return s[tid] - v;
}

// ================= fused: histo (blocks [0,NT)) ∥ x->bf16 cvt (blocks [NT,...)) =================

__global__ __launch_bounds__(256) void k_cvt_histo(const float4* __restrict__ in, uint2* __restrict__ outp,
                                                   int n4, const int* __restrict__ ei,
                                                   int* __restrict__ histT, int E, int NT, int NB) {
    const int tid = threadIdx.x;
    if ((int)blockIdx.x < NT) {
        __shared__ int h[256];
        const int t = blockIdx.x;
        h[tid] = 0;
        __syncthreads();
        const int end = min((t + 1) * TILE, E);
        for (int i = t * TILE + tid; i < end; i += 256)
            atomicAdd(&h[ei[E + i] >> 8], 1);          // LDS atomic
        __syncthreads();
        if (tid < NB) histT[tid * NT + t] = h[tid];
    } else {
        int i = ((int)blockIdx.x - NT) * 256 + tid;
        if (i < n4) {
            float4 v = in[i];
            uint2 o;
            o.x = (f2bf(v.y) << 16) | f2bf(v.x);
            o.y = (f2bf(v.w) << 16) | f2bf(v.z);
            outp[i] = o;
        }
    }
}

// ================= per-bucket tile scan: tilePrefix[b][t] (exclusive over t) + BT[b] =================

__global__ __launch_bounds__(256) void k_tilescan(const int* __restrict__ histT,
                                                  int* __restrict__ tilePrefix,
                                                  int* __restrict__ BT, int NT, int NB) {
    __shared__ int s[256];
    const int b = blockIdx.x;
    const int tid = threadIdx.x;
    int v = (tid < NT) ? histT[b * NT + tid] : 0;
    int ex = block_exscan(v, s);
    if (tid < NT) tilePrefix[b * NT + tid] = ex;
    if (tid == 255) BT[b] = s[255];                    // bucket total
}

// ================= reorder: scatter packed (src<<8)|(dst&255) into per-bucket runs =================
// 512 threads: 8 waves/block for latency hiding. Global offsets reconstructed in-block.

__global__ __launch_bounds__(512) void k_reorder(const int* __restrict__ ei,
                                                 const int* __restrict__ tilePrefix,
                                                 const int* __restrict__ BT,
                                                 unsigned* __restrict__ tmp,
                                                 int E, int NT, int NB) {
    __shared__ int s[512];
    __shared__ int cur[256];
    const int t = blockIdx.x;
    const int tid = threadIdx.x;
    int v = (tid < NB) ? BT[tid] : 0;
    int base = block_exscan512(v, s);
    if (tid < NB) cur[tid] = base + tilePrefix[tid * NT + t];
    __syncthreads();
    const int end = min((t + 1) * TILE, E);
    for (int i = t * TILE + tid; i < end; i += 512) {
        int d = ei[E + i];
        int sv = ei[i];
        int p = atomicAdd(&cur[d >> 8], 1);            // LDS atomic, global slot
        tmp[p] = ((unsigned)sv << 8) | (unsigned)(d & 255);
    }
}

// ================= per-bucket finalize (512 thr, LDS-staged) =================
// Region (~16KB) read once into LDS; histogram + scatter in LDS; csr_src written coalesced.
// Fallback to global 2-pass if bucket exceeds BCAP (correctness distribution-independent).

__global__ __launch_bounds__(512) void k_bucket(const unsigned* __restrict__ tmp,
                                                const int* __restrict__ BT,
                                                int* __restrict__ row_ptr,
                                                float* __restrict__ dinv,
                                                int* __restrict__ csr_src,
                                                int E, int NB, int n) {
    __shared__ int sA[512], ssc[512];
    __shared__ int c[256], lcur[256];
    __shared__ unsigned ebuf[BCAP];
    __shared__ int obuf[BCAP];
    const int b = blockIdx.x;
    const int tid = threadIdx.x;

    int v = (tid < NB) ? BT[tid] : 0;
    (void)block_exscan512(v, sA);                      // sA[i] = inclusive scan of BT
    const int vb = BT[b];
    const int rbeg = sA[b] - vb;                       // exclusive prefix at b
    const bool fits = (vb <= BCAP);

    if (tid < 256) c[tid] = 0;
    __syncthreads();
    if (fits) {
        for (int i = tid; i < vb; i += 512) {
            unsigned w = tmp[rbeg + i];
            ebuf[i] = w;
            atomicAdd(&c[w & 255], 1);                 // LDS histogram
        }
    } else {
        for (int i = tid; i < vb; i += 512)
            atomicAdd(&c[tmp[rbeg + i] & 255], 1);
    }
    __syncthreads();

    int cv = (tid < 256) ? c[tid] : 0;
    int ex = block_exscan512(cv, ssc);                 // local exclusive offsets

    if (tid < 256) {
        const int d = b * 256 + tid;
        if (d < n) {
            row_ptr[d] = rbeg + ex;
            dinv[d] = rsqrtf((float)(c[tid] + 1));     // +1 self-loop
            if (d == n - 1) row_ptr[n] = E;
        }
        lcur[tid] = ex;                                // LOCAL cursor
    }
    __syncthreads();

    if (fits) {
        for (int i = tid; i < vb; i += 512) {
            unsigned w = ebuf[i];
            int p = atomicAdd(&lcur[w & 255], 1);      // LDS atomic, local position
            obuf[p] = (int)(w >> 8);
        }
        __syncthreads();
        for (int i = tid; i < vb; i += 512)
            csr_src[rbeg + i] = obuf[i];               // coalesced dense write
    } else {
        for (int i = tid; i < vb; i += 512) {
            unsigned w = tmp[rbeg + i];
            int p = atomicAdd(&lcur[w & 255], 1);
            csr_src[rbeg + p] = (int)(w >> 8);
        }
    }
}

// ================= MFMA GEMM: H'bf16[M,N] = dinv[row] * (Xbf16[M,128] @ Wf32[128,N]) =================
// 256 thr = 4 waves; wave w owns 16-row strip (M % 16 == 0). mfma_f32_16x16x32_bf16.

template<int N>
__global__ __launch_bounds__(256) void k_gemm_mfma(const unsigned short* __restrict__ X,
                                                   const float* __restrict__ W,
                                                   const float* __restrict__ dinv,
                                                   unsigned short* __restrict__ H, int M) {
    constexpr int K = 128;
    constexpr int LDT = K + 8;                 // pad: 2-way-free b128 reads
    __shared__ unsigned short sWt[N * LDT];

    const int tid = threadIdx.x;
    constexpr int NLOG = (N == 128) ? 7 : 6;
    for (int idx = tid; idx < K * N; idx += 256) {
        int k = idx >> NLOG, c = idx & (N - 1);
        sWt[c * LDT + k] = (unsigned short)f2bf(W[idx]);
    }
    __syncthreads();

    const int wave = __builtin_amdgcn_readfirstlane(tid >> 6);
    const int lane = tid & 63;
    const int m0 = blockIdx.x * 64 + wave * 16;
    if (m0 >= M) return;                        // no syncthreads after this point

    const int arow = lane & 15;
    const int koff = (lane >> 4) * 8;

    const unsigned short* ap = X + (size_t)(m0 + arow) * K + koff;
    short8 a[4];
    #pragma unroll
    for (int q = 0; q < 4; ++q) a[q] = *(const short8*)(ap + q * 32);

    const int row0 = m0 + (lane >> 4) * 4;
    const float4 dv = *(const float4*)(dinv + row0);   // row0 % 4 == 0, dinv 16B-aligned

    #pragma unroll
    for (int ct = 0; ct < N / 16; ++ct) {
        const int bcol = ct * 16 + (lane & 15);
        const unsigned short* bp = &sWt[bcol * LDT + koff];
        f32x4 acc = {0.f, 0.f, 0.f, 0.f};
        #pragma unroll
        for (int q = 0; q < 4; ++q) {
            short8 bq = *(const short8*)(bp + q * 32);
            acc = __builtin_amdgcn_mfma_f32_16x16x32_bf16(a[q], bq, acc, 0, 0, 0);
        }
        const int col = ct * 16 + (lane & 15);
        #pragma unroll
        for (int r = 0; r < 4; ++r) {
            float dr = (r == 0) ? dv.x : (r == 1) ? dv.y : (r == 2) ? dv.z : dv.w;
            H[(size_t)(row0 + r) * N + col] = (unsigned short)f2bf(acc[r] * dr);
        }
    }
}

// ================= aggregation: G=1 — one wave per node, unweighted sum (R16-proven) =================

template<int C, bool RELU, bool OUTBF>
__global__ __launch_bounds__(256) void k_agg(const void* __restrict__ hraw,
                                             const int* __restrict__ row_ptr,
                                             const int* __restrict__ csr_src,
                                             const float* __restrict__ dinv,
                                             const float* __restrict__ bias,
                                             void* __restrict__ agg, int n) {
    constexpr int U = 16;
    constexpr int VPC = C / 64;          // 2 (C=128) or 1 (C=64)
    const int lane = threadIdx.x & 63;
    const int wv = __builtin_amdgcn_readfirstlane(threadIdx.x >> 6);
    const int v = blockIdx.x * 4 + wv;
    if (v >= n) return;

    const unsigned*       hu = (const unsigned*)hraw;        // C=128 view
    const unsigned short* hs = (const unsigned short*)hraw;  // C=64 view

    const int e0 = row_ptr[v], e1 = row_ptr[v + 1];
    const float dd = dinv[v];

    float acc[VPC];
    if (VPC == 2) {
        unsigned t = hu[(size_t)v * 64 + lane];
        acc[0] = bflo(t);
        acc[1] = bfhi(t);
    } else {
        acc[0] = bflo(hs[(size_t)v * 64 + lane]);
    }

    int j0 = e0;
    for (; j0 + U <= e1; j0 += U) {              // full batches: no masks, no multiplies
        int ss[U];
        #pragma unroll
        for (int u = 0; u < U; ++u) ss[u] = csr_src[j0 + u];   // contiguous scalar loads
        float hv[U][VPC];
        #pragma unroll
        for (int u = 0; u < U; ++u) {
            if (VPC == 2) {
                unsigned t = hu[(size_t)ss[u] * 64 + lane];
                hv[u][0] = bflo(t);
                hv[u][1] = bfhi(t);
            } else {
                hv[u][0] = bflo(hs[(size_t)ss[u] * 64 + lane]);
            }
        }
        #pragma unroll
        for (int u = 0; u < U; ++u) {
            acc[0] += hv[u][0];
            if (VPC == 2) acc[1] += hv[u][1];
        }
    }
    if (j0 < e1) {                               // one boundary batch per node
        int ss[U];
        #pragma unroll
        for (int u = 0; u < U; ++u) {
            int sraw = csr_src[j0 + u];          // <=60B overread into next ws buffer
            ss[u] = (j0 + u < e1) ? sraw : v;    // clamp OOB to self row (L1-hot)
        }
        float hv[U][VPC];
        #pragma unroll
        for (int u = 0; u < U; ++u) {
            if (VPC == 2) {
                unsigned t = hu[(size_t)ss[u] * 64 + lane];
                hv[u][0] = bflo(t);
                hv[u][1] = bfhi(t);
            } else {
                hv[u][0] = bflo(hs[(size_t)ss[u] * 64 + lane]);
            }
        }
        #pragma unroll
        for (int u = 0; u < U; ++u) {
            float m = (j0 + u < e1) ? 1.f : 0.f;
            acc[0] = fmaf(m, hv[u][0], acc[0]);
            if (VPC == 2) acc[1] = fmaf(m, hv[u][1], acc[1]);
        }
    }

    if (VPC == 2) {
        float2 bv = ((const float2*)bias)[lane];   // bias[2l], bias[2l+1]
        float ox = acc[0] * dd + bv.x;
        float oy = acc[1] * dd + bv.y;
        if (RELU) { ox = fmaxf(ox, 0.f); oy = fmaxf(oy, 0.f); }
        if (OUTBF) {
            ((unsigned*)agg)[(size_t)v * 64 + lane] = (f2bf(oy) << 16) | f2bf(ox);
        } else {
            ((float2*)agg)[(size_t)v * 64 + lane] = make_float2(ox, oy);
        }
    } else {
        float o = acc[0] * dd + bias[lane];
        if (RELU) o = fmaxf(o, 0.f);
        if (OUTBF) ((unsigned short*)agg)[(size_t)v * 64 + lane] = (unsigned short)f2bf(o);
        else       ((float*)agg)[(size_t)v * 64 + lane] = o;
    }
}

// ================= launch =================

extern "C" void kernel_launch(void* const* d_in, const int* in_sizes, int n_in,
                              void* d_out, int out_size, void* d_ws, size_t ws_size,
                              hipStream_t stream) {
    const float* x  = (const float*)d_in[0];
    const int*   ei = (const int*)d_in[1];
    const float* W1 = (const float*)d_in[2];
    const float* b1 = (const float*)d_in[3];
    const float* W2 = (const float*)d_in[4];
    const float* b2 = (const float*)d_in[5];
    float* out = (float*)d_out;

    const int N = in_sizes[0] / C_IN;   // 50000
    const int E = in_sizes[1] / 2;      // 800000
    const int NT = (E + TILE - 1) / TILE;   // 196 tiles   (<=256 required)
    const int NB = (N + 255) >> 8;          // 196 buckets (<=256 required)
    const int M2 = NB * NT;

    // 16B-aligned workspace layout
    char* base = (char*)d_ws;
    size_t off = 0;
    auto alloc = [&](size_t bytes) {
        char* q = base + off;
        off = (off + bytes + 15) & ~(size_t)15;
        return q;
    };
    int*   histT      = (int*)  alloc((size_t)M2 * 4);
    int*   tilePrefix = (int*)  alloc((size_t)M2 * 4);
    int*   BT         = (int*)  alloc(256 * 4);
    unsigned* tmp     = (unsigned*)alloc((size_t)E * 4);
    int*   row_ptr    = (int*)  alloc((size_t)(N + 1) * 4);
    float* dinv       = (float*)alloc((size_t)N * 4);
    int*   csr_src    = (int*)  alloc((size_t)E * 4);
    unsigned short* xb   = (unsigned short*)alloc((size_t)N * C_IN * 2);   // bf16 x
    unsigned short* h    = (unsigned short*)alloc((size_t)N * C_HID * 2);  // bf16 h' / h2'
    unsigned short* agg1 = (unsigned short*)alloc((size_t)N * C_HID * 2);  // bf16 agg1
    unsigned short* h2   = h;  // layer-2 h' reuses h (dead after agg128)

    dim3 blk(256);
    const int n4 = N * C_IN / 4;
    const int cvtBlocks = (n4 + 255) / 256;

    // 1) fused histo ∥ cvt
    k_cvt_histo<<<NT + cvtBlocks, blk, 0, stream>>>((const float4*)x, (uint2*)xb, n4,
                                                    ei, histT, E, NT, NB);
    // 2) per-bucket tile scan (+ bucket totals)
    k_tilescan<<<NB, blk, 0, stream>>>(histT, tilePrefix, BT, NT, NB);
    // 3) reorder into bucket runs (512 thr)
    k_reorder<<<NT, dim3(512), 0, stream>>>(ei, tilePrefix, BT, tmp, E, NT, NB);
    // 4) per-bucket finalize: row_ptr, dinv, csr_src (512 thr, LDS-staged)
    k_bucket<<<NB, dim3(512), 0, stream>>>(tmp, BT, row_ptr, dinv, csr_src, E, NB, N);

    const int gblocks = (N + 63) / 64;
    const int ablocks = (N + 3) / 4;     // 4 waves x 1 node per block

    // layer 1: h' = dinv * bf16(xb @ W1) ; agg1 = bf16(relu(dinv*(sum h') + b1))
    k_gemm_mfma<C_HID><<<gblocks, blk, 0, stream>>>(xb, W1, dinv, h, N);
    k_agg<C_HID, true, true><<<ablocks, blk, 0, stream>>>(h, row_ptr, csr_src, dinv, b1, agg1, N);

    // layer 2: h2' = dinv * bf16(agg1 @ W2) ; out = dinv*(sum h2') + b2
    k_gemm_mfma<C_OUT><<<gblocks, blk, 0, stream>>>(agg1, W2, dinv, h2, N);
    k_agg<C_OUT, false, false><<<ablocks, blk, 0, stream>>>(h2, row_ptr, csr_src, dinv, b2, out, N);
}

// Round 19
// 110.462 us; speedup vs baseline: 1.8062x; 1.0204x over previous
//
#include <hip/hip_runtime.h>

#define C_IN  128
#define C_HID 128
#define C_OUT 64
#define TILE  4096
#define BCAP  6144   // per-bucket LDS staging capacity (mean 4082, sd ~64; fallback if exceeded)

typedef __attribute__((ext_vector_type(8))) short short8;
typedef __attribute__((ext_vector_type(4))) float f32x4;

// bf16 helpers (RNE)
__device__ __forceinline__ unsigned f2bf(float f) {
    unsigned u = __float_as_uint(f);
    return (u + 0x7FFF + ((u >> 16) & 1)) >> 16;
}
__device__ __forceinline__ float bflo(unsigned t) { return __uint_as_float(t << 16); }
__device__ __forceinline__ float bfhi(unsigned t) { return __uint_as_float(t & 0xFFFF0000u); }

// 256-wide exclusive block scan (Hillis-Steele in LDS). After return, s[255] = total.
__device__ __forceinline__ int block_exscan(int v, int* s) {
    const int tid = threadIdx.x;
    s[tid] = v;
    __syncthreads();
    #pragma unroll
    for (int off = 1; off < 256; off <<= 1) {
        int t = (tid >= off) ? s[tid - off] : 0;
        __syncthreads();
        s[tid] += t;
        __syncthreads();
    }
    return s[tid] - v;
}

// 512-wide variant (values beyond the first 256 lanes are zero-padded by callers).
__device__ __forceinline__ int block_exscan512(int v, int* s) {
    const int tid = threadIdx.x;
    s[tid] = v;
    __syncthreads();
    #pragma unroll
    for (int off = 1; off < 512; off <<= 1) {
        int t = (tid >= off) ? s[tid - off] : 0;
        __syncthreads();
        s[tid] += t;
        __syncthreads();
    }
    return s[tid] - v;
}

// ================= per-tile bucket histogram =================

__global__ __launch_bounds__(256) void k_histo(const int* __restrict__ ei, int* __restrict__ histT,
                                               int E, int NT, int NB) {
    __shared__ int h[256];
    const int t = blockIdx.x;
    const int tid = threadIdx.x;
    h[tid] = 0;
    __syncthreads();
    const int end = min((t + 1) * TILE, E);
    for (int i = t * TILE + tid; i < end; i += 256)
        atomicAdd(&h[ei[E + i] >> 8], 1);              // LDS atomic
    __syncthreads();
    if (tid < NB) histT[tid * NT + t] = h[tid];
}

// ================= per-bucket tile scan: tilePrefix[b][t] (exclusive over t) + BT[b] =================

__global__ __launch_bounds__(256) void k_tilescan(const int* __restrict__ histT,
                                                  int* __restrict__ tilePrefix,
                                                  int* __restrict__ BT, int NT, int NB) {
    __shared__ int s[256];
    const int b = blockIdx.x;
    const int tid = threadIdx.x;
    int v = (tid < NT) ? histT[b * NT + tid] : 0;
    int ex = block_exscan(v, s);
    if (tid < NT) tilePrefix[b * NT + tid] = ex;
    if (tid == 255) BT[b] = s[255];                    // bucket total
}

// ================= reorder: scatter packed (src<<8)|(dst&255) into per-bucket runs =================
// 512 threads: 8 waves/block for latency hiding. Global offsets reconstructed in-block.

__global__ __launch_bounds__(512) void k_reorder(const int* __restrict__ ei,
                                                 const int* __restrict__ tilePrefix,
                                                 const int* __restrict__ BT,
                                                 unsigned* __restrict__ tmp,
                                                 int E, int NT, int NB) {
    __shared__ int s[512];
    __shared__ int cur[256];
    const int t = blockIdx.x;
    const int tid = threadIdx.x;
    int v = (tid < NB) ? BT[tid] : 0;
    int base = block_exscan512(v, s);
    if (tid < NB) cur[tid] = base + tilePrefix[tid * NT + t];
    __syncthreads();
    const int end = min((t + 1) * TILE, E);
    for (int i = t * TILE + tid; i < end; i += 512) {
        int d = ei[E + i];
        int sv = ei[i];
        int p = atomicAdd(&cur[d >> 8], 1);            // LDS atomic, global slot
        tmp[p] = ((unsigned)sv << 8) | (unsigned)(d & 255);
    }
}

// ================= per-bucket finalize (512 thr, LDS-staged) =================

__global__ __launch_bounds__(512) void k_bucket(const unsigned* __restrict__ tmp,
                                                const int* __restrict__ BT,
                                                int* __restrict__ row_ptr,
                                                float* __restrict__ dinv,
                                                int* __restrict__ csr_src,
                                                int E, int NB, int n) {
    __shared__ int sA[512], ssc[512];
    __shared__ int c[256], lcur[256];
    __shared__ unsigned ebuf[BCAP];
    __shared__ int obuf[BCAP];
    const int b = blockIdx.x;
    const int tid = threadIdx.x;

    int v = (tid < NB) ? BT[tid] : 0;
    (void)block_exscan512(v, sA);                      // sA[i] = inclusive scan of BT
    const int vb = BT[b];
    const int rbeg = sA[b] - vb;                       // exclusive prefix at b
    const bool fits = (vb <= BCAP);

    if (tid < 256) c[tid] = 0;
    __syncthreads();
    if (fits) {
        for (int i = tid; i < vb; i += 512) {
            unsigned w = tmp[rbeg + i];
            ebuf[i] = w;
            atomicAdd(&c[w & 255], 1);                 // LDS histogram
        }
    } else {
        for (int i = tid; i < vb; i += 512)
            atomicAdd(&c[tmp[rbeg + i] & 255], 1);
    }
    __syncthreads();

    int cv = (tid < 256) ? c[tid] : 0;
    int ex = block_exscan512(cv, ssc);                 // local exclusive offsets

    if (tid < 256) {
        const int d = b * 256 + tid;
        if (d < n) {
            row_ptr[d] = rbeg + ex;
            dinv[d] = rsqrtf((float)(c[tid] + 1));     // +1 self-loop
            if (d == n - 1) row_ptr[n] = E;
        }
        lcur[tid] = ex;                                // LOCAL cursor
    }
    __syncthreads();

    if (fits) {
        for (int i = tid; i < vb; i += 512) {
            unsigned w = ebuf[i];
            int p = atomicAdd(&lcur[w & 255], 1);      // LDS atomic, local position
            obuf[p] = (int)(w >> 8);
        }
        __syncthreads();
        for (int i = tid; i < vb; i += 512)
            csr_src[rbeg + i] = obuf[i];               // coalesced dense write
    } else {
        for (int i = tid; i < vb; i += 512) {
            unsigned w = tmp[rbeg + i];
            int p = atomicAdd(&lcur[w & 255], 1);
            csr_src[rbeg + p] = (int)(w >> 8);
        }
    }
}

// ================= MFMA GEMM: H'bf16[M,N] = dinv[row] * (X[M,128] @ Wf32[128,N]) =================
// 256 thr = 4 waves; wave w owns 16-row strip (M % 16 == 0). mfma_f32_16x16x32_bf16.
// F32IN: A-fragments read from f32 x directly (2 aligned float4/lane) and converted
// in-register with the same RNE f2bf — bitwise-identical to the old cvt-pass path,
// but skips the 38MB xb round-trip entirely.

template<int N, bool F32IN>
__global__ __launch_bounds__(256) void k_gemm_mfma(const void* __restrict__ Xraw,
                                                   const float* __restrict__ W,
                                                   const float* __restrict__ dinv,
                                                   unsigned short* __restrict__ H, int M) {
    constexpr int K = 128;
    constexpr int LDT = K + 8;                 // pad: 2-way-free b128 reads
    __shared__ unsigned short sWt[N * LDT];

    const int tid = threadIdx.x;
    constexpr int NLOG = (N == 128) ? 7 : 6;
    for (int idx = tid; idx < K * N; idx += 256) {
        int k = idx >> NLOG, c = idx & (N - 1);
        sWt[c * LDT + k] = (unsigned short)f2bf(W[idx]);
    }
    __syncthreads();

    const int wave = __builtin_amdgcn_readfirstlane(tid >> 6);
    const int lane = tid & 63;
    const int m0 = blockIdx.x * 64 + wave * 16;
    if (m0 >= M) return;                        // no syncthreads after this point

    const int arow = lane & 15;
    const int koff = (lane >> 4) * 8;           // 0,8,16,24 -> f32 addr 32B-aligned

    short8 a[4];
    if (F32IN) {
        const float* apf = (const float*)Xraw + (size_t)(m0 + arow) * K + koff;
        #pragma unroll
        for (int q = 0; q < 4; ++q) {
            float4 v0 = *(const float4*)(apf + q * 32);
            float4 v1 = *(const float4*)(apf + q * 32 + 4);
            short8 t;
            t[0] = (short)f2bf(v0.x); t[1] = (short)f2bf(v0.y);
            t[2] = (short)f2bf(v0.z); t[3] = (short)f2bf(v0.w);
            t[4] = (short)f2bf(v1.x); t[5] = (short)f2bf(v1.y);
            t[6] = (short)f2bf(v1.z); t[7] = (short)f2bf(v1.w);
            a[q] = t;
        }
    } else {
        const unsigned short* ap = (const unsigned short*)Xraw + (size_t)(m0 + arow) * K + koff;
        #pragma unroll
        for (int q = 0; q < 4; ++q) a[q] = *(const short8*)(ap + q * 32);
    }

    const int row0 = m0 + (lane >> 4) * 4;
    const float4 dv = *(const float4*)(dinv + row0);   // row0 % 4 == 0, dinv 16B-aligned

    #pragma unroll
    for (int ct = 0; ct < N / 16; ++ct) {
        const int bcol = ct * 16 + (lane & 15);
        const unsigned short* bp = &sWt[bcol * LDT + koff];
        f32x4 acc = {0.f, 0.f, 0.f, 0.f};
        #pragma unroll
        for (int q = 0; q < 4; ++q) {
            short8 bq = *(const short8*)(bp + q * 32);
            acc = __builtin_amdgcn_mfma_f32_16x16x32_bf16(a[q], bq, acc, 0, 0, 0);
        }
        const int col = ct * 16 + (lane & 15);
        #pragma unroll
        for (int r = 0; r < 4; ++r) {
            float dr = (r == 0) ? dv.x : (r == 1) ? dv.y : (r == 2) ? dv.z : dv.w;
            H[(size_t)(row0 + r) * N + col] = (unsigned short)f2bf(acc[r] * dr);
        }
    }
}

// ================= aggregation: G=1 — one wave per node, unweighted sum (R16-proven) =================

template<int C, bool RELU, bool OUTBF>
__global__ __launch_bounds__(256) void k_agg(const void* __restrict__ hraw,
                                             const int* __restrict__ row_ptr,
                                             const int* __restrict__ csr_src,
                                             const float* __restrict__ dinv,
                                             const float* __restrict__ bias,
                                             void* __restrict__ agg, int n) {
    constexpr int U = 16;
    constexpr int VPC = C / 64;          // 2 (C=128) or 1 (C=64)
    const int lane = threadIdx.x & 63;
    const int wv = __builtin_amdgcn_readfirstlane(threadIdx.x >> 6);
    const int v = blockIdx.x * 4 + wv;
    if (v >= n) return;

    const unsigned*       hu = (const unsigned*)hraw;        // C=128 view
    const unsigned short* hs = (const unsigned short*)hraw;  // C=64 view

    const int e0 = row_ptr[v], e1 = row_ptr[v + 1];
    const float dd = dinv[v];

    float acc[VPC];
    if (VPC == 2) {
        unsigned t = hu[(size_t)v * 64 + lane];
        acc[0] = bflo(t);
        acc[1] = bfhi(t);
    } else {
        acc[0] = bflo(hs[(size_t)v * 64 + lane]);
    }

    int j0 = e0;
    for (; j0 + U <= e1; j0 += U) {              // full batches: no masks, no multiplies
        int ss[U];
        #pragma unroll
        for (int u = 0; u < U; ++u) ss[u] = csr_src[j0 + u];   // contiguous scalar loads
        float hv[U][VPC];
        #pragma unroll
        for (int u = 0; u < U; ++u) {
            if (VPC == 2) {
                unsigned t = hu[(size_t)ss[u] * 64 + lane];
                hv[u][0] = bflo(t);
                hv[u][1] = bfhi(t);
            } else {
                hv[u][0] = bflo(hs[(size_t)ss[u] * 64 + lane]);
            }
        }
        #pragma unroll
        for (int u = 0; u < U; ++u) {
            acc[0] += hv[u][0];
            if (VPC == 2) acc[1] += hv[u][1];
        }
    }
    if (j0 < e1) {                               // one boundary batch per node
        int ss[U];
        #pragma unroll
        for (int u = 0; u < U; ++u) {
            int sraw = csr_src[j0 + u];          // <=60B overread into next ws buffer
            ss[u] = (j0 + u < e1) ? sraw : v;    // clamp OOB to self row (L1-hot)
        }
        float hv[U][VPC];
        #pragma unroll
        for (int u = 0; u < U; ++u) {
            if (VPC == 2) {
                unsigned t = hu[(size_t)ss[u] * 64 + lane];
                hv[u][0] = bflo(t);
                hv[u][1] = bfhi(t);
            } else {
                hv[u][0] = bflo(hs[(size_t)ss[u] * 64 + lane]);
            }
        }
        #pragma unroll
        for (int u = 0; u < U; ++u) {
            float m = (j0 + u < e1) ? 1.f : 0.f;
            acc[0] = fmaf(m, hv[u][0], acc[0]);
            if (VPC == 2) acc[1] = fmaf(m, hv[u][1], acc[1]);
        }
    }

    if (VPC == 2) {
        float2 bv = ((const float2*)bias)[lane];   // bias[2l], bias[2l+1]
        float ox = acc[0] * dd + bv.x;
        float oy = acc[1] * dd + bv.y;
        if (RELU) { ox = fmaxf(ox, 0.f); oy = fmaxf(oy, 0.f); }
        if (OUTBF) {
            ((unsigned*)agg)[(size_t)v * 64 + lane] = (f2bf(oy) << 16) | f2bf(ox);
        } else {
            ((float2*)agg)[(size_t)v * 64 + lane] = make_float2(ox, oy);
        }
    } else {
        float o = acc[0] * dd + bias[lane];
        if (RELU) o = fmaxf(o, 0.f);
        if (OUTBF) ((unsigned short*)agg)[(size_t)v * 64 + lane] = (unsigned short)f2bf(o);
        else       ((float*)agg)[(size_t)v * 64 + lane] = o;
    }
}

// ================= launch =================

extern "C" void kernel_launch(void* const* d_in, const int* in_sizes, int n_in,
                              void* d_out, int out_size, void* d_ws, size_t ws_size,
                              hipStream_t stream) {
    const float* x  = (const float*)d_in[0];
    const int*   ei = (const int*)d_in[1];
    const float* W1 = (const float*)d_in[2];
    const float* b1 = (const float*)d_in[3];
    const float* W2 = (const float*)d_in[4];
    const float* b2 = (const float*)d_in[5];
    float* out = (float*)d_out;

    const int N = in_sizes[0] / C_IN;   // 50000
    const int E = in_sizes[1] / 2;      // 800000
    const int NT = (E + TILE - 1) / TILE;   // 196 tiles   (<=256 required)
    const int NB = (N + 255) >> 8;          // 196 buckets (<=256 required)
    const int M2 = NB * NT;

    // 16B-aligned workspace layout
    char* base = (char*)d_ws;
    size_t off = 0;
    auto alloc = [&](size_t bytes) {
        char* q = base + off;
        off = (off + bytes + 15) & ~(size_t)15;
        return q;
    };
    int*   histT      = (int*)  alloc((size_t)M2 * 4);
    int*   tilePrefix = (int*)  alloc((size_t)M2 * 4);
    int*   BT         = (int*)  alloc(256 * 4);
    unsigned* tmp     = (unsigned*)alloc((size_t)E * 4);
    int*   row_ptr    = (int*)  alloc((size_t)(N + 1) * 4);
    float* dinv       = (float*)alloc((size_t)N * 4);
    int*   csr_src    = (int*)  alloc((size_t)E * 4);
    unsigned short* h    = (unsigned short*)alloc((size_t)N * C_HID * 2);  // bf16 h' / h2'
    unsigned short* agg1 = (unsigned short*)alloc((size_t)N * C_HID * 2);  // bf16 agg1
    unsigned short* h2   = h;  // layer-2 h' reuses h (dead after agg128)

    dim3 blk(256);

    // CSR build (no global atomics)
    k_histo   <<<NT, blk, 0, stream>>>(ei, histT, E, NT, NB);
    k_tilescan<<<NB, blk, 0, stream>>>(histT, tilePrefix, BT, NT, NB);
    k_reorder <<<NT, dim3(512), 0, stream>>>(ei, tilePrefix, BT, tmp, E, NT, NB);
    k_bucket  <<<NB, dim3(512), 0, stream>>>(tmp, BT, row_ptr, dinv, csr_src, E, NB, N);

    const int gblocks = (N + 63) / 64;
    const int ablocks = (N + 3) / 4;     // 4 waves x 1 node per block

    // layer 1: h' = dinv * bf16(x @ W1) (f32 A-read, in-register cvt) ; agg1 = bf16(relu(...))
    k_gemm_mfma<C_HID, true><<<gblocks, blk, 0, stream>>>(x, W1, dinv, h, N);
    k_agg<C_HID, true, true><<<ablocks, blk, 0, stream>>>(h, row_ptr, csr_src, dinv, b1, agg1, N);

    // layer 2: h2' = dinv * bf16(agg1 @ W2) ; out = dinv*(sum h2') + b2
    k_gemm_mfma<C_OUT, false><<<gblocks, blk, 0, stream>>>(agg1, W2, dinv, h2, N);
    k_agg<C_OUT, false, false><<<ablocks, blk, 0, stream>>>(h2, row_ptr, csr_src, dinv, b2, out, N);
}